// Round 2
// baseline (1808.503 us; speedup 1.0000x reference)
//
#include <hip/hip_runtime.h>
#include <hip/hip_bf16.h>

#define NNODES 100000
#define NEDGES 3200000
#define NFEAT 128
#define HID 64
#define NGRAPHS 128

// ---------------- CSR build ----------------
// NOTE: harness passes integer inputs as int32 (NOT int64, despite JAX ref dtype).

__global__ void k_count(const int* __restrict__ ei, int* __restrict__ deg, int nE) {
    int e = blockIdx.x * 256 + threadIdx.x;
    if (e < nE) atomicAdd(&deg[ei[nE + e]], 1);
}

__global__ void k_dinv(const int* __restrict__ deg, float* __restrict__ dinv, int n) {
    int i = blockIdx.x * 256 + threadIdx.x;
    if (i < n) dinv[i] = 1.0f / sqrtf((float)deg[i] + 1.0f);
}

__global__ void k_scan1(const int* __restrict__ deg, int* __restrict__ ptr,
                        int* __restrict__ bsum, int n) {
    __shared__ int sm[512];
    int t = threadIdx.x, i = blockIdx.x * 512 + t;
    int v = (i < n) ? deg[i] : 0;
    sm[t] = v; __syncthreads();
    for (int off = 1; off < 512; off <<= 1) {
        int a = (t >= off) ? sm[t - off] : 0;
        __syncthreads();
        sm[t] += a;
        __syncthreads();
    }
    if (i < n) ptr[i] = sm[t] - v;          // exclusive within block
    if (t == 511) bsum[blockIdx.x] = sm[511];
}

__global__ void k_scan2(const int* __restrict__ bsum, int* __restrict__ boff, int nb) {
    __shared__ int sm[512];
    int t = threadIdx.x;
    int v = (t < nb) ? bsum[t] : 0;
    sm[t] = v; __syncthreads();
    for (int off = 1; off < 512; off <<= 1) {
        int a = (t >= off) ? sm[t - off] : 0;
        __syncthreads();
        sm[t] += a;
        __syncthreads();
    }
    if (t < nb) boff[t] = sm[t] - v;
}

__global__ void k_scan3(int* __restrict__ ptr, const int* __restrict__ boff,
                        int* __restrict__ cursor, int n, int nE) {
    int i = blockIdx.x * 512 + threadIdx.x;
    if (i < n) {
        int v = ptr[i] + boff[blockIdx.x];
        ptr[i] = v;
        cursor[i] = v;
    }
    if (i == 0) ptr[n] = nE;
}

__global__ void k_scatter(const int* __restrict__ ei, int* __restrict__ cursor,
                          int* __restrict__ csrc, int nE) {
    int e = blockIdx.x * 256 + threadIdx.x;
    if (e < nE) {
        int d = ei[nE + e];
        int s = ei[e];
        int p = atomicAdd(&cursor[d], 1);
        csrc[p] = s;
    }
}

// ---------------- GEMM: Y[r][c] = dinv[r] * sum_k X[r][k] W[k][c],  c in [0,64) ----------------

template<int KT>
__global__ __launch_bounds__(256) void k_gemm(const float* __restrict__ X,
                                              const float* __restrict__ W,
                                              const float* __restrict__ dinv,
                                              float* __restrict__ Y, int n) {
    __shared__ float sXT[64][65];   // [k][row], padded: conflict-free read & write
    __shared__ float sW[64][64];    // [k][c]
    int t = threadIdx.x;
    int brow = blockIdx.x * 64;
    int row = t >> 2, c0 = (t & 3) << 4;
    float acc[16];
#pragma unroll
    for (int j = 0; j < 16; ++j) acc[j] = 0.f;

    for (int kt = 0; kt < KT; kt += 64) {
#pragma unroll
        for (int j = 0; j < 16; ++j) {     // load X tile transposed
            int idx = t + j * 256;         // 0..4095
            int r = idx >> 6, c = idx & 63;
            int gr = brow + r;
            float v = (gr < n) ? X[(size_t)gr * KT + kt + c] : 0.f;
            sXT[c][r] = v;
        }
#pragma unroll
        for (int j = 0; j < 16; ++j) {     // load W tile
            int idx = t + j * 256;
            int k = idx >> 6, c = idx & 63;
            sW[k][c] = W[(size_t)(kt + k) * 64 + c];
        }
        __syncthreads();
#pragma unroll
        for (int k = 0; k < 64; ++k) {
            float xv = sXT[k][row];
#pragma unroll
            for (int j = 0; j < 16; ++j)
                acc[j] = fmaf(xv, sW[k][c0 + j], acc[j]);
        }
        __syncthreads();
    }
    int gr = brow + row;
    if (gr < n) {
        float s = dinv[gr];
#pragma unroll
        for (int j = 0; j < 16; ++j)
            Y[(size_t)gr * 64 + c0 + j] = acc[j] * s;
    }
}

// ---------------- Gather aggregation: one wave per node, lane = feature ----------------

template<bool RELU>
__global__ __launch_bounds__(256) void k_gather(const float* __restrict__ Yin,
                                                const int* __restrict__ ptr,
                                                const int* __restrict__ csrc,
                                                const float* __restrict__ dinv,
                                                const float* __restrict__ bias,
                                                float* __restrict__ out, int n) {
    int node = blockIdx.x * 4 + (threadIdx.x >> 6);
    int lane = threadIdx.x & 63;
    if (node >= n) return;
    float acc = Yin[(size_t)node * 64 + lane];   // self-loop term (already dinv-scaled)
    int s = ptr[node], e = ptr[node + 1];
    int k = s;
    for (; k + 4 <= e; k += 4) {                 // 4 loads in flight
        int s0 = csrc[k], s1 = csrc[k + 1], s2 = csrc[k + 2], s3 = csrc[k + 3];
        float v0 = Yin[(size_t)s0 * 64 + lane];
        float v1 = Yin[(size_t)s1 * 64 + lane];
        float v2 = Yin[(size_t)s2 * 64 + lane];
        float v3 = Yin[(size_t)s3 * 64 + lane];
        acc += v0 + v1 + v2 + v3;
    }
    for (; k < e; ++k) acc += Yin[(size_t)csrc[k] * 64 + lane];
    float r = fmaf(dinv[node], acc, bias[lane]);
    if (RELU) r = fmaxf(r, 0.f);
    out[(size_t)node * 64 + lane] = r;
}

// ---------------- Pool + readout ----------------

__global__ void k_pool(const float* __restrict__ h, const int* __restrict__ batch,
                       float* __restrict__ sums, float* __restrict__ cnt, int n) {
    int i = blockIdx.x * 256 + threadIdx.x;
    if (i < n * 64) {
        int node = i >> 6, f = i & 63;
        int g = batch[node];
        atomicAdd(&sums[g * 64 + f], h[i]);
        if (f == 0) atomicAdd(&cnt[g], 1.f);
    }
}

__global__ void k_final(const float* __restrict__ sums, const float* __restrict__ cnt,
                        const float* __restrict__ Wlin, const float* __restrict__ blin,
                        float* __restrict__ out) {
    int i = blockIdx.x * 128 + threadIdx.x;
    if (i < NGRAPHS * 10) {
        int g = i / 10, c = i % 10;
        float inv = 1.f / fmaxf(cnt[g], 1.f);
        float acc = 0.f;
#pragma unroll
        for (int hh = 0; hh < 64; ++hh)
            acc += sums[g * 64 + hh] * Wlin[hh * 10 + c];
        out[i] = acc * inv + blin[c];
    }
}

// ---------------- launch ----------------

extern "C" void kernel_launch(void* const* d_in, const int* in_sizes, int n_in,
                              void* d_out, int out_size, void* d_ws, size_t ws_size,
                              hipStream_t stream) {
    const float* x     = (const float*)d_in[0];
    const int*   ei    = (const int*)d_in[1];    // int32 per harness contract
    const int*   batch = (const int*)d_in[2];    // int32 per harness contract
    const float* W1    = (const float*)d_in[3];
    const float* b1    = (const float*)d_in[4];
    const float* W2    = (const float*)d_in[5];
    const float* b2    = (const float*)d_in[6];
    const float* Wlin  = (const float*)d_in[7];
    const float* blin  = (const float*)d_in[8];
    float* out = (float*)d_out;

    int n  = in_sizes[0] / NFEAT;   // 100000
    int nE = in_sizes[1] / 2;       // 3200000

    char* ws = (char*)d_ws;
    auto alloc = [&](size_t b) -> void* {
        void* p = (void*)ws;
        ws += (b + 255) & ~(size_t)255;
        return p;
    };
    int*   deg    = (int*)alloc((size_t)n * 4);
    float* dinv   = (float*)alloc((size_t)n * 4);
    int*   ptr    = (int*)alloc((size_t)(n + 1) * 4);
    int*   cursor = (int*)alloc((size_t)n * 4);
    int*   bsum   = (int*)alloc(4096);
    int*   boff   = (int*)alloc(4096);
    int*   csrc   = (int*)alloc((size_t)nE * 4);
    float* bufA   = (float*)alloc((size_t)n * HID * 4);
    float* bufB   = (float*)alloc((size_t)n * HID * 4);
    float* sums   = (float*)alloc((size_t)NGRAPHS * HID * 4);
    float* cnt    = (float*)alloc((size_t)NGRAPHS * 4);

    hipMemsetAsync(deg, 0, (size_t)n * 4, stream);
    hipMemsetAsync(sums, 0, (size_t)NGRAPHS * HID * 4, stream);
    hipMemsetAsync(cnt, 0, (size_t)NGRAPHS * 4, stream);

    int nb = (n + 511) / 512;   // 196

    k_count<<<(nE + 255) / 256, 256, 0, stream>>>(ei, deg, nE);
    k_dinv<<<(n + 255) / 256, 256, 0, stream>>>(deg, dinv, n);
    k_scan1<<<nb, 512, 0, stream>>>(deg, ptr, bsum, n);
    k_scan2<<<1, 512, 0, stream>>>(bsum, boff, nb);
    k_scan3<<<nb, 512, 0, stream>>>(ptr, boff, cursor, n, nE);
    k_scatter<<<(nE + 255) / 256, 256, 0, stream>>>(ei, cursor, csrc, nE);

    k_gemm<NFEAT><<<(n + 63) / 64, 256, 0, stream>>>(x, W1, dinv, bufA, n);
    k_gather<true><<<(n + 3) / 4, 256, 0, stream>>>(bufA, ptr, csrc, dinv, b1, bufB, n);
    k_gemm<HID><<<(n + 63) / 64, 256, 0, stream>>>(bufB, W2, dinv, bufA, n);
    k_gather<false><<<(n + 3) / 4, 256, 0, stream>>>(bufA, ptr, csrc, dinv, b2, bufB, n);

    k_pool<<<((size_t)n * 64 + 255) / 256, 256, 0, stream>>>(bufB, batch, sums, cnt, n);
    k_final<<<10, 128, 0, stream>>>(sums, cnt, Wlin, blin, out);
}

// Round 3
// 1301.037 us; speedup vs baseline: 1.3900x; 1.3900x over previous
//
#include <hip/hip_runtime.h>
#include <hip/hip_bf16.h>

#define NNODES 100000
#define NEDGES 3200000
#define NFEAT 128
#define HID 64
#define NGRAPHS 128
#define POOL_CHUNK 256

// ---------------- CSR build ----------------
// NOTE: harness passes integer inputs as int32 (NOT int64, despite JAX ref dtype).

__global__ void k_count(const int* __restrict__ ei, int* __restrict__ deg, int nE) {
    int e = blockIdx.x * 256 + threadIdx.x;
    if (e < nE) atomicAdd(&deg[ei[nE + e]], 1);
}

__global__ void k_dinv(const int* __restrict__ deg, float* __restrict__ dinv, int n) {
    int i = blockIdx.x * 256 + threadIdx.x;
    if (i < n) dinv[i] = 1.0f / sqrtf((float)deg[i] + 1.0f);
}

__global__ void k_scan1(const int* __restrict__ deg, int* __restrict__ ptr,
                        int* __restrict__ bsum, int n) {
    __shared__ int sm[512];
    int t = threadIdx.x, i = blockIdx.x * 512 + t;
    int v = (i < n) ? deg[i] : 0;
    sm[t] = v; __syncthreads();
    for (int off = 1; off < 512; off <<= 1) {
        int a = (t >= off) ? sm[t - off] : 0;
        __syncthreads();
        sm[t] += a;
        __syncthreads();
    }
    if (i < n) ptr[i] = sm[t] - v;          // exclusive within block
    if (t == 511) bsum[blockIdx.x] = sm[511];
}

__global__ void k_scan2(const int* __restrict__ bsum, int* __restrict__ boff, int nb) {
    __shared__ int sm[512];
    int t = threadIdx.x;
    int v = (t < nb) ? bsum[t] : 0;
    sm[t] = v; __syncthreads();
    for (int off = 1; off < 512; off <<= 1) {
        int a = (t >= off) ? sm[t - off] : 0;
        __syncthreads();
        sm[t] += a;
        __syncthreads();
    }
    if (t < nb) boff[t] = sm[t] - v;
}

__global__ void k_scan3(int* __restrict__ ptr, const int* __restrict__ boff,
                        int* __restrict__ cursor, int n, int nE) {
    int i = blockIdx.x * 512 + threadIdx.x;
    if (i < n) {
        int v = ptr[i] + boff[blockIdx.x];
        ptr[i] = v;
        cursor[i] = v;
    }
    if (i == 0) ptr[n] = nE;
}

__global__ void k_scatter(const int* __restrict__ ei, int* __restrict__ cursor,
                          int* __restrict__ csrc, int nE) {
    int e = blockIdx.x * 256 + threadIdx.x;
    if (e < nE) {
        int d = ei[nE + e];
        int s = ei[e];
        int p = atomicAdd(&cursor[d], 1);
        csrc[p] = s;
    }
}

// ---------------- GEMM: Y[r][c] = dinv[r] * sum_k X[r][k] W[k][c],  c in [0,64) ----------------

template<int KT>
__global__ __launch_bounds__(256) void k_gemm(const float* __restrict__ X,
                                              const float* __restrict__ W,
                                              const float* __restrict__ dinv,
                                              float* __restrict__ Y, int n) {
    __shared__ float sXT[64][65];   // [k][row], padded: conflict-free read & write
    __shared__ float sW[64][64];    // [k][c]
    int t = threadIdx.x;
    int brow = blockIdx.x * 64;
    int row = t >> 2, c0 = (t & 3) << 4;
    float acc[16];
#pragma unroll
    for (int j = 0; j < 16; ++j) acc[j] = 0.f;

    for (int kt = 0; kt < KT; kt += 64) {
#pragma unroll
        for (int j = 0; j < 16; ++j) {     // load X tile transposed
            int idx = t + j * 256;         // 0..4095
            int r = idx >> 6, c = idx & 63;
            int gr = brow + r;
            float v = (gr < n) ? X[(size_t)gr * KT + kt + c] : 0.f;
            sXT[c][r] = v;
        }
#pragma unroll
        for (int j = 0; j < 16; ++j) {     // load W tile
            int idx = t + j * 256;
            int k = idx >> 6, c = idx & 63;
            sW[k][c] = W[(size_t)(kt + k) * 64 + c];
        }
        __syncthreads();
#pragma unroll
        for (int k = 0; k < 64; ++k) {
            float xv = sXT[k][row];
#pragma unroll
            for (int j = 0; j < 16; ++j)
                acc[j] = fmaf(xv, sW[k][c0 + j], acc[j]);
        }
        __syncthreads();
    }
    int gr = brow + row;
    if (gr < n) {
        float s = dinv[gr];
#pragma unroll
        for (int j = 0; j < 16; ++j)
            Y[(size_t)gr * 64 + c0 + j] = acc[j] * s;
    }
}

// ---------------- Gather aggregation: one wave per node, float4 lanes ----------------
// 16 lanes x float4 cover one 64-float row; 4 edge-groups per wave; 2-deep unroll
// => 8 independent 16B loads in flight per wave.

template<bool RELU>
__global__ __launch_bounds__(256) void k_gather4(const float4* __restrict__ Yin,
                                                 const int* __restrict__ ptr,
                                                 const int* __restrict__ csrc,
                                                 const float* __restrict__ dinv,
                                                 const float4* __restrict__ bias4,
                                                 float4* __restrict__ out, int n) {
    int node = blockIdx.x * 4 + (threadIdx.x >> 6);
    int lane = threadIdx.x & 63;
    int q  = lane >> 4;      // edge-group 0..3
    int f4 = lane & 15;      // float4 index within row
    if (node >= n) return;
    int s = ptr[node], e = ptr[node + 1];
    float4 acc = make_float4(0.f, 0.f, 0.f, 0.f);
    int k = s + q;
    while (k + 4 < e) {
        int s0 = csrc[k], s1 = csrc[k + 4];
        float4 v0 = Yin[(size_t)s0 * 16 + f4];
        float4 v1 = Yin[(size_t)s1 * 16 + f4];
        acc.x += v0.x + v1.x; acc.y += v0.y + v1.y;
        acc.z += v0.z + v1.z; acc.w += v0.w + v1.w;
        k += 8;
    }
    if (k < e) {
        int s0 = csrc[k];
        float4 v0 = Yin[(size_t)s0 * 16 + f4];
        acc.x += v0.x; acc.y += v0.y; acc.z += v0.z; acc.w += v0.w;
    }
    // combine the 4 edge-groups (butterfly over lane bits 4,5)
#pragma unroll
    for (int m = 16; m <= 32; m <<= 1) {
        acc.x += __shfl_xor(acc.x, m);
        acc.y += __shfl_xor(acc.y, m);
        acc.z += __shfl_xor(acc.z, m);
        acc.w += __shfl_xor(acc.w, m);
    }
    if (q == 0) {
        float4 self = Yin[(size_t)node * 16 + f4];   // already dinv-scaled
        float di = dinv[node];
        float4 b = bias4[f4];
        float4 r;
        r.x = fmaf(di, acc.x + self.x, b.x);
        r.y = fmaf(di, acc.y + self.y, b.y);
        r.z = fmaf(di, acc.z + self.z, b.z);
        r.w = fmaf(di, acc.w + self.w, b.w);
        if (RELU) {
            r.x = fmaxf(r.x, 0.f); r.y = fmaxf(r.y, 0.f);
            r.z = fmaxf(r.z, 0.f); r.w = fmaxf(r.w, 0.f);
        }
        out[(size_t)node * 16 + f4] = r;
    }
}

// ---------------- Pool: batch is SORTED -> segmented register accumulation ----------------
// One wave per POOL_CHUNK contiguous nodes, lane = feature. Atomics only at
// segment boundaries: ~50K total instead of 6.4M.

__global__ __launch_bounds__(256) void k_pool2(const float* __restrict__ h,
                                               const int* __restrict__ batch,
                                               float* __restrict__ sums,
                                               float* __restrict__ cnt, int n) {
    int wave = blockIdx.x * 4 + (threadIdx.x >> 6);
    int lane = threadIdx.x & 63;
    int start = wave * POOL_CHUNK;
    if (start >= n) return;
    int end = min(start + POOL_CHUNK, n);
    int g = batch[start];
    float acc = 0.f;
    int cl = 0;
    for (int i = start; i < end; ++i) {
        int gi = batch[i];
        if (gi != g) {
            atomicAdd(&sums[g * 64 + lane], acc);
            if (lane == 0) atomicAdd(&cnt[g], (float)cl);
            acc = 0.f; cl = 0; g = gi;
        }
        acc += h[(size_t)i * 64 + lane];
        ++cl;
    }
    atomicAdd(&sums[g * 64 + lane], acc);
    if (lane == 0) atomicAdd(&cnt[g], (float)cl);
}

__global__ void k_final(const float* __restrict__ sums, const float* __restrict__ cnt,
                        const float* __restrict__ Wlin, const float* __restrict__ blin,
                        float* __restrict__ out) {
    int i = blockIdx.x * 128 + threadIdx.x;
    if (i < NGRAPHS * 10) {
        int g = i / 10, c = i % 10;
        float inv = 1.f / fmaxf(cnt[g], 1.f);
        float acc = 0.f;
#pragma unroll
        for (int hh = 0; hh < 64; ++hh)
            acc += sums[g * 64 + hh] * Wlin[hh * 10 + c];
        out[i] = acc * inv + blin[c];
    }
}

// ---------------- launch ----------------

extern "C" void kernel_launch(void* const* d_in, const int* in_sizes, int n_in,
                              void* d_out, int out_size, void* d_ws, size_t ws_size,
                              hipStream_t stream) {
    const float* x     = (const float*)d_in[0];
    const int*   ei    = (const int*)d_in[1];    // int32 per harness contract
    const int*   batch = (const int*)d_in[2];    // int32 per harness contract
    const float* W1    = (const float*)d_in[3];
    const float* b1    = (const float*)d_in[4];
    const float* W2    = (const float*)d_in[5];
    const float* b2    = (const float*)d_in[6];
    const float* Wlin  = (const float*)d_in[7];
    const float* blin  = (const float*)d_in[8];
    float* out = (float*)d_out;

    int n  = in_sizes[0] / NFEAT;   // 100000
    int nE = in_sizes[1] / 2;       // 3200000

    char* ws = (char*)d_ws;
    auto alloc = [&](size_t b) -> void* {
        void* p = (void*)ws;
        ws += (b + 255) & ~(size_t)255;
        return p;
    };
    int*   deg    = (int*)alloc((size_t)n * 4);
    float* dinv   = (float*)alloc((size_t)n * 4);
    int*   ptr    = (int*)alloc((size_t)(n + 1) * 4);
    int*   cursor = (int*)alloc((size_t)n * 4);
    int*   bsum   = (int*)alloc(4096);
    int*   boff   = (int*)alloc(4096);
    int*   csrc   = (int*)alloc((size_t)nE * 4);
    float* bufA   = (float*)alloc((size_t)n * HID * 4);
    float* bufB   = (float*)alloc((size_t)n * HID * 4);
    float* sums   = (float*)alloc((size_t)NGRAPHS * HID * 4);
    float* cnt    = (float*)alloc((size_t)NGRAPHS * 4);

    hipMemsetAsync(deg, 0, (size_t)n * 4, stream);
    hipMemsetAsync(sums, 0, (size_t)NGRAPHS * HID * 4, stream);
    hipMemsetAsync(cnt, 0, (size_t)NGRAPHS * 4, stream);

    int nb = (n + 511) / 512;   // 196

    k_count<<<(nE + 255) / 256, 256, 0, stream>>>(ei, deg, nE);
    k_dinv<<<(n + 255) / 256, 256, 0, stream>>>(deg, dinv, n);
    k_scan1<<<nb, 512, 0, stream>>>(deg, ptr, bsum, n);
    k_scan2<<<1, 512, 0, stream>>>(bsum, boff, nb);
    k_scan3<<<nb, 512, 0, stream>>>(ptr, boff, cursor, n, nE);
    k_scatter<<<(nE + 255) / 256, 256, 0, stream>>>(ei, cursor, csrc, nE);

    k_gemm<NFEAT><<<(n + 63) / 64, 256, 0, stream>>>(x, W1, dinv, bufA, n);
    k_gather4<true><<<(n + 3) / 4, 256, 0, stream>>>((const float4*)bufA, ptr, csrc,
                                                     dinv, (const float4*)b1,
                                                     (float4*)bufB, n);
    k_gemm<HID><<<(n + 63) / 64, 256, 0, stream>>>(bufB, W2, dinv, bufA, n);
    k_gather4<false><<<(n + 3) / 4, 256, 0, stream>>>((const float4*)bufA, ptr, csrc,
                                                      dinv, (const float4*)b2,
                                                      (float4*)bufB, n);

    int pool_waves = (n + POOL_CHUNK - 1) / POOL_CHUNK;
    k_pool2<<<(pool_waves + 3) / 4, 256, 0, stream>>>(bufB, batch, sums, cnt, n);
    k_final<<<10, 128, 0, stream>>>(sums, cnt, Wlin, blin, out);
}

// Round 4
// 896.063 us; speedup vs baseline: 2.0183x; 1.4519x over previous
//
#include <hip/hip_runtime.h>
#include <hip/hip_bf16.h>

#define NNODES 100000
#define NEDGES 3200000
#define NFEAT 128
#define HID 64
#define NGRAPHS 128
#define POOL_CHUNK 256

// ---------------- CSR build ----------------
// NOTE: harness passes integer inputs as int32 (NOT int64, despite JAX ref dtype).

__global__ void k_count(const int* __restrict__ ei, int* __restrict__ deg, int nE) {
    int e = blockIdx.x * 256 + threadIdx.x;
    if (e < nE) atomicAdd(&deg[ei[nE + e]], 1);
}

__global__ void k_dinv(const int* __restrict__ deg, float* __restrict__ dinv, int n) {
    int i = blockIdx.x * 256 + threadIdx.x;
    if (i < n) dinv[i] = 1.0f / sqrtf((float)deg[i] + 1.0f);
}

__global__ void k_scan1(const int* __restrict__ deg, int* __restrict__ ptr,
                        int* __restrict__ bsum, int n) {
    __shared__ int sm[512];
    int t = threadIdx.x, i = blockIdx.x * 512 + t;
    int v = (i < n) ? deg[i] : 0;
    sm[t] = v; __syncthreads();
    for (int off = 1; off < 512; off <<= 1) {
        int a = (t >= off) ? sm[t - off] : 0;
        __syncthreads();
        sm[t] += a;
        __syncthreads();
    }
    if (i < n) ptr[i] = sm[t] - v;          // exclusive within block
    if (t == 511) bsum[blockIdx.x] = sm[511];
}

__global__ void k_scan2(const int* __restrict__ bsum, int* __restrict__ boff, int nb) {
    __shared__ int sm[512];
    int t = threadIdx.x;
    int v = (t < nb) ? bsum[t] : 0;
    sm[t] = v; __syncthreads();
    for (int off = 1; off < 512; off <<= 1) {
        int a = (t >= off) ? sm[t - off] : 0;
        __syncthreads();
        sm[t] += a;
        __syncthreads();
    }
    if (t < nb) boff[t] = sm[t] - v;
}

__global__ void k_scan3(int* __restrict__ ptr, const int* __restrict__ boff,
                        int* __restrict__ cursor, int n, int nE) {
    int i = blockIdx.x * 512 + threadIdx.x;
    if (i < n) {
        int v = ptr[i] + boff[blockIdx.x];
        ptr[i] = v;
        cursor[i] = v;
    }
    if (i == 0) ptr[n] = nE;
}

__global__ void k_scatter(const int* __restrict__ ei, int* __restrict__ cursor,
                          int* __restrict__ csrc, int nE) {
    int e = blockIdx.x * 256 + threadIdx.x;
    if (e < nE) {
        int d = ei[nE + e];
        int s = ei[e];
        int p = atomicAdd(&cursor[d], 1);
        csrc[p] = s;
    }
}

// ---------------- GEMM: Y[r][c] = dinv[r] * sum_k X[r][k] W[k][c],  c in [0,64) ----------------
// Round-4 rewrite: VGPR-capped (launch_bounds min-waves=4 => <=128 VGPR),
// unroll 4 (not 64) to stop spill-inducing full pipelining, float4 LDS/global I/O.

template<int KT>
__global__ __launch_bounds__(256, 4) void k_gemm(const float* __restrict__ X,
                                                 const float* __restrict__ W,
                                                 const float* __restrict__ dinv,
                                                 float* __restrict__ Y, int n) {
    __shared__ __align__(16) float sXT[64][65];   // [k][row], padded
    __shared__ __align__(16) float sW[64][64];    // [k][c]
    int t = threadIdx.x;
    int brow = blockIdx.x * 64;
    int row = t >> 2, c0 = (t & 3) << 4;
    float4 a0 = make_float4(0.f, 0.f, 0.f, 0.f);
    float4 a1 = a0, a2 = a0, a3 = a0;

    for (int kt = 0; kt < KT; kt += 64) {
        {   // X tile (64x64 floats) as float4, stored transposed
            const float4* X4 = (const float4*)X;
            int rs = KT >> 2;                    // row stride in float4
#pragma unroll
            for (int j = 0; j < 4; ++j) {
                int idx = t + j * 256;           // 0..1023
                int r = idx >> 4, c4 = idx & 15;
                int gr = brow + r;
                float4 v = make_float4(0.f, 0.f, 0.f, 0.f);
                if (gr < n) v = X4[(size_t)gr * rs + (kt >> 2) + c4];
                int c = c4 << 2;
                sXT[c][r] = v.x; sXT[c + 1][r] = v.y;
                sXT[c + 2][r] = v.z; sXT[c + 3][r] = v.w;
            }
        }
        {   // W tile (64x64) as float4
            const float4* W4 = (const float4*)W; // row stride 16 float4
#pragma unroll
            for (int j = 0; j < 4; ++j) {
                int idx = t + j * 256;
                int k = idx >> 4, c4 = idx & 15;
                *(float4*)&sW[k][c4 << 2] = W4[(size_t)(kt + k) * 16 + c4];
            }
        }
        __syncthreads();
#pragma unroll 4
        for (int k = 0; k < 64; ++k) {
            float xv = sXT[k][row];
            float4 w0 = *(const float4*)&sW[k][c0];
            float4 w1 = *(const float4*)&sW[k][c0 + 4];
            float4 w2 = *(const float4*)&sW[k][c0 + 8];
            float4 w3 = *(const float4*)&sW[k][c0 + 12];
            a0.x = fmaf(xv, w0.x, a0.x); a0.y = fmaf(xv, w0.y, a0.y);
            a0.z = fmaf(xv, w0.z, a0.z); a0.w = fmaf(xv, w0.w, a0.w);
            a1.x = fmaf(xv, w1.x, a1.x); a1.y = fmaf(xv, w1.y, a1.y);
            a1.z = fmaf(xv, w1.z, a1.z); a1.w = fmaf(xv, w1.w, a1.w);
            a2.x = fmaf(xv, w2.x, a2.x); a2.y = fmaf(xv, w2.y, a2.y);
            a2.z = fmaf(xv, w2.z, a2.z); a2.w = fmaf(xv, w2.w, a2.w);
            a3.x = fmaf(xv, w3.x, a3.x); a3.y = fmaf(xv, w3.y, a3.y);
            a3.z = fmaf(xv, w3.z, a3.z); a3.w = fmaf(xv, w3.w, a3.w);
        }
        __syncthreads();
    }
    int gr = brow + row;
    if (gr < n) {
        float s = dinv[gr];
        a0.x *= s; a0.y *= s; a0.z *= s; a0.w *= s;
        a1.x *= s; a1.y *= s; a1.z *= s; a1.w *= s;
        a2.x *= s; a2.y *= s; a2.z *= s; a2.w *= s;
        a3.x *= s; a3.y *= s; a3.z *= s; a3.w *= s;
        float4* Y4 = (float4*)Y;
        size_t base = (size_t)gr * 16 + (c0 >> 2);
        Y4[base + 0] = a0; Y4[base + 1] = a1;
        Y4[base + 2] = a2; Y4[base + 3] = a3;
    }
}

// ---------------- Gather aggregation: one wave per node, float4 lanes ----------------

template<bool RELU>
__global__ __launch_bounds__(256) void k_gather4(const float4* __restrict__ Yin,
                                                 const int* __restrict__ ptr,
                                                 const int* __restrict__ csrc,
                                                 const float* __restrict__ dinv,
                                                 const float4* __restrict__ bias4,
                                                 float4* __restrict__ out, int n) {
    int node = blockIdx.x * 4 + (threadIdx.x >> 6);
    int lane = threadIdx.x & 63;
    int q  = lane >> 4;      // edge-group 0..3
    int f4 = lane & 15;      // float4 index within row
    if (node >= n) return;
    int s = ptr[node], e = ptr[node + 1];
    float4 acc = make_float4(0.f, 0.f, 0.f, 0.f);
    int k = s + q;
    while (k + 4 < e) {
        int s0 = csrc[k], s1 = csrc[k + 4];
        float4 v0 = Yin[(size_t)s0 * 16 + f4];
        float4 v1 = Yin[(size_t)s1 * 16 + f4];
        acc.x += v0.x + v1.x; acc.y += v0.y + v1.y;
        acc.z += v0.z + v1.z; acc.w += v0.w + v1.w;
        k += 8;
    }
    if (k < e) {
        int s0 = csrc[k];
        float4 v0 = Yin[(size_t)s0 * 16 + f4];
        acc.x += v0.x; acc.y += v0.y; acc.z += v0.z; acc.w += v0.w;
    }
#pragma unroll
    for (int m = 16; m <= 32; m <<= 1) {
        acc.x += __shfl_xor(acc.x, m);
        acc.y += __shfl_xor(acc.y, m);
        acc.z += __shfl_xor(acc.z, m);
        acc.w += __shfl_xor(acc.w, m);
    }
    if (q == 0) {
        float4 self = Yin[(size_t)node * 16 + f4];   // already dinv-scaled
        float di = dinv[node];
        float4 b = bias4[f4];
        float4 r;
        r.x = fmaf(di, acc.x + self.x, b.x);
        r.y = fmaf(di, acc.y + self.y, b.y);
        r.z = fmaf(di, acc.z + self.z, b.z);
        r.w = fmaf(di, acc.w + self.w, b.w);
        if (RELU) {
            r.x = fmaxf(r.x, 0.f); r.y = fmaxf(r.y, 0.f);
            r.z = fmaxf(r.z, 0.f); r.w = fmaxf(r.w, 0.f);
        }
        out[(size_t)node * 16 + f4] = r;
    }
}

// ---------------- Pool: batch is SORTED -> segmented register accumulation ----------------

__global__ __launch_bounds__(256) void k_pool2(const float* __restrict__ h,
                                               const int* __restrict__ batch,
                                               float* __restrict__ sums,
                                               float* __restrict__ cnt, int n) {
    int wave = blockIdx.x * 4 + (threadIdx.x >> 6);
    int lane = threadIdx.x & 63;
    int start = wave * POOL_CHUNK;
    if (start >= n) return;
    int end = min(start + POOL_CHUNK, n);
    int g = batch[start];
    float acc = 0.f;
    int cl = 0;
    for (int i = start; i < end; ++i) {
        int gi = batch[i];
        if (gi != g) {
            atomicAdd(&sums[g * 64 + lane], acc);
            if (lane == 0) atomicAdd(&cnt[g], (float)cl);
            acc = 0.f; cl = 0; g = gi;
        }
        acc += h[(size_t)i * 64 + lane];
        ++cl;
    }
    atomicAdd(&sums[g * 64 + lane], acc);
    if (lane == 0) atomicAdd(&cnt[g], (float)cl);
}

__global__ void k_final(const float* __restrict__ sums, const float* __restrict__ cnt,
                        const float* __restrict__ Wlin, const float* __restrict__ blin,
                        float* __restrict__ out) {
    int i = blockIdx.x * 128 + threadIdx.x;
    if (i < NGRAPHS * 10) {
        int g = i / 10, c = i % 10;
        float inv = 1.f / fmaxf(cnt[g], 1.f);
        float acc = 0.f;
#pragma unroll
        for (int hh = 0; hh < 64; ++hh)
            acc += sums[g * 64 + hh] * Wlin[hh * 10 + c];
        out[i] = acc * inv + blin[c];
    }
}

// ---------------- launch ----------------

extern "C" void kernel_launch(void* const* d_in, const int* in_sizes, int n_in,
                              void* d_out, int out_size, void* d_ws, size_t ws_size,
                              hipStream_t stream) {
    const float* x     = (const float*)d_in[0];
    const int*   ei    = (const int*)d_in[1];    // int32 per harness contract
    const int*   batch = (const int*)d_in[2];    // int32 per harness contract
    const float* W1    = (const float*)d_in[3];
    const float* b1    = (const float*)d_in[4];
    const float* W2    = (const float*)d_in[5];
    const float* b2    = (const float*)d_in[6];
    const float* Wlin  = (const float*)d_in[7];
    const float* blin  = (const float*)d_in[8];
    float* out = (float*)d_out;

    int n  = in_sizes[0] / NFEAT;   // 100000
    int nE = in_sizes[1] / 2;       // 3200000

    char* ws = (char*)d_ws;
    auto alloc = [&](size_t b) -> void* {
        void* p = (void*)ws;
        ws += (b + 255) & ~(size_t)255;
        return p;
    };
    int*   deg    = (int*)alloc((size_t)n * 4);
    float* dinv   = (float*)alloc((size_t)n * 4);
    int*   ptr    = (int*)alloc((size_t)(n + 1) * 4);
    int*   cursor = (int*)alloc((size_t)n * 4);
    int*   bsum   = (int*)alloc(4096);
    int*   boff   = (int*)alloc(4096);
    int*   csrc   = (int*)alloc((size_t)nE * 4);
    float* bufA   = (float*)alloc((size_t)n * HID * 4);
    float* bufB   = (float*)alloc((size_t)n * HID * 4);
    float* sums   = (float*)alloc((size_t)NGRAPHS * HID * 4);
    float* cnt    = (float*)alloc((size_t)NGRAPHS * 4);

    hipMemsetAsync(deg, 0, (size_t)n * 4, stream);
    hipMemsetAsync(sums, 0, (size_t)NGRAPHS * HID * 4, stream);
    hipMemsetAsync(cnt, 0, (size_t)NGRAPHS * 4, stream);

    int nb = (n + 511) / 512;   // 196

    k_count<<<(nE + 255) / 256, 256, 0, stream>>>(ei, deg, nE);
    k_dinv<<<(n + 255) / 256, 256, 0, stream>>>(deg, dinv, n);
    k_scan1<<<nb, 512, 0, stream>>>(deg, ptr, bsum, n);
    k_scan2<<<1, 512, 0, stream>>>(bsum, boff, nb);
    k_scan3<<<nb, 512, 0, stream>>>(ptr, boff, cursor, n, nE);
    k_scatter<<<(nE + 255) / 256, 256, 0, stream>>>(ei, cursor, csrc, nE);

    k_gemm<NFEAT><<<(n + 63) / 64, 256, 0, stream>>>(x, W1, dinv, bufA, n);
    k_gather4<true><<<(n + 3) / 4, 256, 0, stream>>>((const float4*)bufA, ptr, csrc,
                                                     dinv, (const float4*)b1,
                                                     (float4*)bufB, n);
    k_gemm<HID><<<(n + 63) / 64, 256, 0, stream>>>(bufB, W2, dinv, bufA, n);
    k_gather4<false><<<(n + 3) / 4, 256, 0, stream>>>((const float4*)bufA, ptr, csrc,
                                                      dinv, (const float4*)b2,
                                                      (float4*)bufB, n);

    int pool_waves = (n + POOL_CHUNK - 1) / POOL_CHUNK;
    k_pool2<<<(pool_waves + 3) / 4, 256, 0, stream>>>(bufB, batch, sums, cnt, n);
    k_final<<<10, 128, 0, stream>>>(sums, cnt, Wlin, blin, out);
}

// Round 5
// 679.971 us; speedup vs baseline: 2.6597x; 1.3178x over previous
//
#include <hip/hip_runtime.h>
#include <hip/hip_bf16.h>

#define NNODES 100000
#define NEDGES 3200000
#define NFEAT 128
#define HID 64
#define NGRAPHS 128
#define POOL_CHUNK 256

// ---------------- CSR build ----------------
// NOTE: harness passes integer inputs as int32 (NOT int64, despite JAX ref dtype).
// Round-5: k_count captures the atomicAdd return as the edge's rank within its
// dst segment -> scatter needs NO atomics (csrc[ptr[d]+rank[e]] = s).

__global__ __launch_bounds__(256) void k_count_rank(const int* __restrict__ ei,
                                                    int* __restrict__ deg,
                                                    int* __restrict__ rank, int nE) {
    int base = blockIdx.x * 1024 + threadIdx.x;
#pragma unroll
    for (int j = 0; j < 4; ++j) {
        int e = base + j * 256;
        if (e < nE) {
            int d = ei[nE + e];
            rank[e] = atomicAdd(&deg[d], 1);
        }
    }
}

__global__ void k_dinv(const int* __restrict__ deg, float* __restrict__ dinv, int n) {
    int i = blockIdx.x * 256 + threadIdx.x;
    if (i < n) dinv[i] = 1.0f / sqrtf((float)deg[i] + 1.0f);
}

__global__ void k_scan1(const int* __restrict__ deg, int* __restrict__ ptr,
                        int* __restrict__ bsum, int n) {
    __shared__ int sm[512];
    int t = threadIdx.x, i = blockIdx.x * 512 + t;
    int v = (i < n) ? deg[i] : 0;
    sm[t] = v; __syncthreads();
    for (int off = 1; off < 512; off <<= 1) {
        int a = (t >= off) ? sm[t - off] : 0;
        __syncthreads();
        sm[t] += a;
        __syncthreads();
    }
    if (i < n) ptr[i] = sm[t] - v;          // exclusive within block
    if (t == 511) bsum[blockIdx.x] = sm[511];
}

__global__ void k_scan2(const int* __restrict__ bsum, int* __restrict__ boff, int nb) {
    __shared__ int sm[512];
    int t = threadIdx.x;
    int v = (t < nb) ? bsum[t] : 0;
    sm[t] = v; __syncthreads();
    for (int off = 1; off < 512; off <<= 1) {
        int a = (t >= off) ? sm[t - off] : 0;
        __syncthreads();
        sm[t] += a;
        __syncthreads();
    }
    if (t < nb) boff[t] = sm[t] - v;
}

__global__ void k_scan3(int* __restrict__ ptr, const int* __restrict__ boff,
                        int n, int nE) {
    int i = blockIdx.x * 512 + threadIdx.x;
    if (i < n) ptr[i] += boff[blockIdx.x];
    if (i == 0) ptr[n] = nE;
}

__global__ __launch_bounds__(256) void k_scatter(const int* __restrict__ ei,
                                                 const int* __restrict__ rank,
                                                 const int* __restrict__ ptr,
                                                 int* __restrict__ csrc, int nE) {
    int base = blockIdx.x * 1024 + threadIdx.x;
    int e0 = base, e1 = base + 256, e2 = base + 512, e3 = base + 768;
    int d0 = 0, d1 = 0, d2 = 0, d3 = 0;
    if (e0 < nE) d0 = ei[nE + e0];
    if (e1 < nE) d1 = ei[nE + e1];
    if (e2 < nE) d2 = ei[nE + e2];
    if (e3 < nE) d3 = ei[nE + e3];
    if (e0 < nE) csrc[ptr[d0] + rank[e0]] = ei[e0];
    if (e1 < nE) csrc[ptr[d1] + rank[e1]] = ei[e1];
    if (e2 < nE) csrc[ptr[d2] + rank[e2]] = ei[e2];
    if (e3 < nE) csrc[ptr[d3] + rank[e3]] = ei[e3];
}

// ---------------- GEMM: Y[r][c] = dinv[r] * sum_k X[r][k] W[k][c],  c in [0,64) ----------------
// VGPR-capped (launch_bounds min-waves=4), unroll 4, float4 LDS/global I/O.

template<int KT>
__global__ __launch_bounds__(256, 4) void k_gemm(const float* __restrict__ X,
                                                 const float* __restrict__ W,
                                                 const float* __restrict__ dinv,
                                                 float* __restrict__ Y, int n) {
    __shared__ __align__(16) float sXT[64][65];   // [k][row], padded
    __shared__ __align__(16) float sW[64][64];    // [k][c]
    int t = threadIdx.x;
    int brow = blockIdx.x * 64;
    int row = t >> 2, c0 = (t & 3) << 4;
    float4 a0 = make_float4(0.f, 0.f, 0.f, 0.f);
    float4 a1 = a0, a2 = a0, a3 = a0;

    for (int kt = 0; kt < KT; kt += 64) {
        {   // X tile (64x64 floats) as float4, stored transposed
            const float4* X4 = (const float4*)X;
            int rs = KT >> 2;                    // row stride in float4
#pragma unroll
            for (int j = 0; j < 4; ++j) {
                int idx = t + j * 256;           // 0..1023
                int r = idx >> 4, c4 = idx & 15;
                int gr = brow + r;
                float4 v = make_float4(0.f, 0.f, 0.f, 0.f);
                if (gr < n) v = X4[(size_t)gr * rs + (kt >> 2) + c4];
                int c = c4 << 2;
                sXT[c][r] = v.x; sXT[c + 1][r] = v.y;
                sXT[c + 2][r] = v.z; sXT[c + 3][r] = v.w;
            }
        }
        {   // W tile (64x64) as float4
            const float4* W4 = (const float4*)W; // row stride 16 float4
#pragma unroll
            for (int j = 0; j < 4; ++j) {
                int idx = t + j * 256;
                int k = idx >> 4, c4 = idx & 15;
                *(float4*)&sW[k][c4 << 2] = W4[(size_t)(kt + k) * 16 + c4];
            }
        }
        __syncthreads();
#pragma unroll 4
        for (int k = 0; k < 64; ++k) {
            float xv = sXT[k][row];
            float4 w0 = *(const float4*)&sW[k][c0];
            float4 w1 = *(const float4*)&sW[k][c0 + 4];
            float4 w2 = *(const float4*)&sW[k][c0 + 8];
            float4 w3 = *(const float4*)&sW[k][c0 + 12];
            a0.x = fmaf(xv, w0.x, a0.x); a0.y = fmaf(xv, w0.y, a0.y);
            a0.z = fmaf(xv, w0.z, a0.z); a0.w = fmaf(xv, w0.w, a0.w);
            a1.x = fmaf(xv, w1.x, a1.x); a1.y = fmaf(xv, w1.y, a1.y);
            a1.z = fmaf(xv, w1.z, a1.z); a1.w = fmaf(xv, w1.w, a1.w);
            a2.x = fmaf(xv, w2.x, a2.x); a2.y = fmaf(xv, w2.y, a2.y);
            a2.z = fmaf(xv, w2.z, a2.z); a2.w = fmaf(xv, w2.w, a2.w);
            a3.x = fmaf(xv, w3.x, a3.x); a3.y = fmaf(xv, w3.y, a3.y);
            a3.z = fmaf(xv, w3.z, a3.z); a3.w = fmaf(xv, w3.w, a3.w);
        }
        __syncthreads();
    }
    int gr = brow + row;
    if (gr < n) {
        float s = dinv[gr];
        a0.x *= s; a0.y *= s; a0.z *= s; a0.w *= s;
        a1.x *= s; a1.y *= s; a1.z *= s; a1.w *= s;
        a2.x *= s; a2.y *= s; a2.z *= s; a2.w *= s;
        a3.x *= s; a3.y *= s; a3.z *= s; a3.w *= s;
        float4* Y4 = (float4*)Y;
        size_t base = (size_t)gr * 16 + (c0 >> 2);
        Y4[base + 0] = a0; Y4[base + 1] = a1;
        Y4[base + 2] = a2; Y4[base + 3] = a3;
    }
}

// ---------------- Gather aggregation: one wave per node, float4 lanes ----------------

template<bool RELU>
__global__ __launch_bounds__(256) void k_gather4(const float4* __restrict__ Yin,
                                                 const int* __restrict__ ptr,
                                                 const int* __restrict__ csrc,
                                                 const float* __restrict__ dinv,
                                                 const float4* __restrict__ bias4,
                                                 float4* __restrict__ out, int n) {
    int node = blockIdx.x * 4 + (threadIdx.x >> 6);
    int lane = threadIdx.x & 63;
    int q  = lane >> 4;      // edge-group 0..3
    int f4 = lane & 15;      // float4 index within row
    if (node >= n) return;
    int s = ptr[node], e = ptr[node + 1];
    float4 acc = make_float4(0.f, 0.f, 0.f, 0.f);
    int k = s + q;
    while (k + 4 < e) {
        int s0 = csrc[k], s1 = csrc[k + 4];
        float4 v0 = Yin[(size_t)s0 * 16 + f4];
        float4 v1 = Yin[(size_t)s1 * 16 + f4];
        acc.x += v0.x + v1.x; acc.y += v0.y + v1.y;
        acc.z += v0.z + v1.z; acc.w += v0.w + v1.w;
        k += 8;
    }
    if (k < e) {
        int s0 = csrc[k];
        float4 v0 = Yin[(size_t)s0 * 16 + f4];
        acc.x += v0.x; acc.y += v0.y; acc.z += v0.z; acc.w += v0.w;
    }
#pragma unroll
    for (int m = 16; m <= 32; m <<= 1) {
        acc.x += __shfl_xor(acc.x, m);
        acc.y += __shfl_xor(acc.y, m);
        acc.z += __shfl_xor(acc.z, m);
        acc.w += __shfl_xor(acc.w, m);
    }
    if (q == 0) {
        float4 self = Yin[(size_t)node * 16 + f4];   // already dinv-scaled
        float di = dinv[node];
        float4 b = bias4[f4];
        float4 r;
        r.x = fmaf(di, acc.x + self.x, b.x);
        r.y = fmaf(di, acc.y + self.y, b.y);
        r.z = fmaf(di, acc.z + self.z, b.z);
        r.w = fmaf(di, acc.w + self.w, b.w);
        if (RELU) {
            r.x = fmaxf(r.x, 0.f); r.y = fmaxf(r.y, 0.f);
            r.z = fmaxf(r.z, 0.f); r.w = fmaxf(r.w, 0.f);
        }
        out[(size_t)node * 16 + f4] = r;
    }
}

// ---------------- Pool: batch is SORTED -> segmented register accumulation ----------------

__global__ __launch_bounds__(256) void k_pool2(const float* __restrict__ h,
                                               const int* __restrict__ batch,
                                               float* __restrict__ sums,
                                               float* __restrict__ cnt, int n) {
    int wave = blockIdx.x * 4 + (threadIdx.x >> 6);
    int lane = threadIdx.x & 63;
    int start = wave * POOL_CHUNK;
    if (start >= n) return;
    int end = min(start + POOL_CHUNK, n);
    int g = batch[start];
    float acc = 0.f;
    int cl = 0;
    for (int i = start; i < end; ++i) {
        int gi = batch[i];
        if (gi != g) {
            atomicAdd(&sums[g * 64 + lane], acc);
            if (lane == 0) atomicAdd(&cnt[g], (float)cl);
            acc = 0.f; cl = 0; g = gi;
        }
        acc += h[(size_t)i * 64 + lane];
        ++cl;
    }
    atomicAdd(&sums[g * 64 + lane], acc);
    if (lane == 0) atomicAdd(&cnt[g], (float)cl);
}

__global__ void k_final(const float* __restrict__ sums, const float* __restrict__ cnt,
                        const float* __restrict__ Wlin, const float* __restrict__ blin,
                        float* __restrict__ out) {
    int i = blockIdx.x * 128 + threadIdx.x;
    if (i < NGRAPHS * 10) {
        int g = i / 10, c = i % 10;
        float inv = 1.f / fmaxf(cnt[g], 1.f);
        float acc = 0.f;
#pragma unroll
        for (int hh = 0; hh < 64; ++hh)
            acc += sums[g * 64 + hh] * Wlin[hh * 10 + c];
        out[i] = acc * inv + blin[c];
    }
}

// ---------------- launch ----------------

extern "C" void kernel_launch(void* const* d_in, const int* in_sizes, int n_in,
                              void* d_out, int out_size, void* d_ws, size_t ws_size,
                              hipStream_t stream) {
    const float* x     = (const float*)d_in[0];
    const int*   ei    = (const int*)d_in[1];    // int32 per harness contract
    const int*   batch = (const int*)d_in[2];    // int32 per harness contract
    const float* W1    = (const float*)d_in[3];
    const float* b1    = (const float*)d_in[4];
    const float* W2    = (const float*)d_in[5];
    const float* b2    = (const float*)d_in[6];
    const float* Wlin  = (const float*)d_in[7];
    const float* blin  = (const float*)d_in[8];
    float* out = (float*)d_out;

    int n  = in_sizes[0] / NFEAT;   // 100000
    int nE = in_sizes[1] / 2;       // 3200000

    char* ws = (char*)d_ws;
    auto alloc = [&](size_t b) -> void* {
        void* p = (void*)ws;
        ws += (b + 255) & ~(size_t)255;
        return p;
    };
    int*   deg    = (int*)alloc((size_t)n * 4);
    float* dinv   = (float*)alloc((size_t)n * 4);
    int*   ptr    = (int*)alloc((size_t)(n + 1) * 4);
    int*   rank   = (int*)alloc((size_t)nE * 4);
    int*   bsum   = (int*)alloc(4096);
    int*   boff   = (int*)alloc(4096);
    int*   csrc   = (int*)alloc((size_t)nE * 4);
    float* bufA   = (float*)alloc((size_t)n * HID * 4);
    float* bufB   = (float*)alloc((size_t)n * HID * 4);
    float* sums   = (float*)alloc((size_t)NGRAPHS * HID * 4);
    float* cnt    = (float*)alloc((size_t)NGRAPHS * 4);

    hipMemsetAsync(deg, 0, (size_t)n * 4, stream);
    hipMemsetAsync(sums, 0, (size_t)NGRAPHS * HID * 4, stream);
    hipMemsetAsync(cnt, 0, (size_t)NGRAPHS * 4, stream);

    int nb = (n + 511) / 512;   // 196

    k_count_rank<<<(nE + 1023) / 1024, 256, 0, stream>>>(ei, deg, rank, nE);
    k_dinv<<<(n + 255) / 256, 256, 0, stream>>>(deg, dinv, n);
    k_scan1<<<nb, 512, 0, stream>>>(deg, ptr, bsum, n);
    k_scan2<<<1, 512, 0, stream>>>(bsum, boff, nb);
    k_scan3<<<nb, 512, 0, stream>>>(ptr, boff, n, nE);
    k_scatter<<<(nE + 1023) / 1024, 256, 0, stream>>>(ei, rank, ptr, csrc, nE);

    k_gemm<NFEAT><<<(n + 63) / 64, 256, 0, stream>>>(x, W1, dinv, bufA, n);
    k_gather4<true><<<(n + 3) / 4, 256, 0, stream>>>((const float4*)bufA, ptr, csrc,
                                                     dinv, (const float4*)b1,
                                                     (float4*)bufB, n);
    k_gemm<HID><<<(n + 63) / 64, 256, 0, stream>>>(bufB, W2, dinv, bufA, n);
    k_gather4<false><<<(n + 3) / 4, 256, 0, stream>>>((const float4*)bufA, ptr, csrc,
                                                      dinv, (const float4*)b2,
                                                      (float4*)bufB, n);

    int pool_waves = (n + POOL_CHUNK - 1) / POOL_CHUNK;
    k_pool2<<<(pool_waves + 3) / 4, 256, 0, stream>>>(bufB, batch, sums, cnt, n);
    k_final<<<10, 128, 0, stream>>>(sums, cnt, Wlin, blin, out);
}

// Round 6
// 638.306 us; speedup vs baseline: 2.8333x; 1.0653x over previous
//
#include <hip/hip_runtime.h>
#include <hip/hip_bf16.h>

#define NNODES 100000
#define NEDGES 3200000
#define NFEAT 128
#define HID 64
#define NGRAPHS 128
#define POOL_CHUNK 256

// NOTE: harness passes integer inputs as int32 (NOT int64, despite JAX ref dtype).

// ---------------- Fused GEMM1 (raw xW1) + count_rank ----------------
// blockIdx % 3 == 0 -> GEMM tile; else -> count/rank chunk. The atomic-bound
// count waves (VALU ~0%) co-schedule with VALU-bound GEMM waves on the CUs.

__global__ __launch_bounds__(256, 4) void k_gemm1_count(
    const float* __restrict__ X, const float* __restrict__ W,
    const int* __restrict__ ei, int* __restrict__ deg,
    unsigned short* __restrict__ rank,
    float* __restrict__ Y, int n, int nE) {
    __shared__ __align__(16) float sXT[64][65];
    __shared__ __align__(16) float sW[64][64];
    int bid = blockIdx.x;
    int qb = bid / 3, rb = bid - qb * 3;
    if (rb == 0) {
        // ---- GEMM block qb: rows [qb*64, qb*64+64), Y = X @ W1 (raw, no dinv)
        int t = threadIdx.x;
        int brow = qb * 64;
        int row = t >> 2, c0 = (t & 3) << 4;
        float4 a0 = make_float4(0.f, 0.f, 0.f, 0.f);
        float4 a1 = a0, a2 = a0, a3 = a0;
        for (int kt = 0; kt < NFEAT; kt += 64) {
            const float4* X4 = (const float4*)X;
            const int rs = NFEAT >> 2;
#pragma unroll
            for (int j = 0; j < 4; ++j) {
                int idx = t + j * 256;
                int r = idx >> 4, c4 = idx & 15;
                int gr = brow + r;
                float4 v = make_float4(0.f, 0.f, 0.f, 0.f);
                if (gr < n) v = X4[(size_t)gr * rs + (kt >> 2) + c4];
                int c = c4 << 2;
                sXT[c][r] = v.x; sXT[c + 1][r] = v.y;
                sXT[c + 2][r] = v.z; sXT[c + 3][r] = v.w;
            }
            const float4* W4 = (const float4*)W;
#pragma unroll
            for (int j = 0; j < 4; ++j) {
                int idx = t + j * 256;
                int k = idx >> 4, c4 = idx & 15;
                *(float4*)&sW[k][c4 << 2] = W4[(size_t)(kt + k) * 16 + c4];
            }
            __syncthreads();
#pragma unroll 4
            for (int k = 0; k < 64; ++k) {
                float xv = sXT[k][row];
                float4 w0 = *(const float4*)&sW[k][c0];
                float4 w1 = *(const float4*)&sW[k][c0 + 4];
                float4 w2 = *(const float4*)&sW[k][c0 + 8];
                float4 w3 = *(const float4*)&sW[k][c0 + 12];
                a0.x = fmaf(xv, w0.x, a0.x); a0.y = fmaf(xv, w0.y, a0.y);
                a0.z = fmaf(xv, w0.z, a0.z); a0.w = fmaf(xv, w0.w, a0.w);
                a1.x = fmaf(xv, w1.x, a1.x); a1.y = fmaf(xv, w1.y, a1.y);
                a1.z = fmaf(xv, w1.z, a1.z); a1.w = fmaf(xv, w1.w, a1.w);
                a2.x = fmaf(xv, w2.x, a2.x); a2.y = fmaf(xv, w2.y, a2.y);
                a2.z = fmaf(xv, w2.z, a2.z); a2.w = fmaf(xv, w2.w, a2.w);
                a3.x = fmaf(xv, w3.x, a3.x); a3.y = fmaf(xv, w3.y, a3.y);
                a3.z = fmaf(xv, w3.z, a3.z); a3.w = fmaf(xv, w3.w, a3.w);
            }
            __syncthreads();
        }
        int gr = brow + row;
        if (gr < n) {
            float4* Y4 = (float4*)Y;
            size_t base = (size_t)gr * 16 + (c0 >> 2);
            Y4[base + 0] = a0; Y4[base + 1] = a1;
            Y4[base + 2] = a2; Y4[base + 3] = a3;
        }
    } else {
        // ---- count/rank chunk: cb in [0, 3125]; edges [cb*1024, cb*1024+1024)
        int cb = 2 * qb + (rb - 1);
        int base = cb * 1024 + threadIdx.x;
#pragma unroll
        for (int j = 0; j < 4; ++j) {
            int e = base + j * 256;
            if (e < nE) {
                int d = ei[nE + e];
                rank[e] = (unsigned short)atomicAdd(&deg[d], 1);
            }
        }
    }
}

__global__ void k_dinv(const int* __restrict__ deg, float* __restrict__ dinv, int n) {
    int i = blockIdx.x * 256 + threadIdx.x;
    if (i < n) dinv[i] = 1.0f / sqrtf((float)deg[i] + 1.0f);
}

__global__ void k_scan1(const int* __restrict__ deg, int* __restrict__ ptr,
                        int* __restrict__ bsum, int n) {
    __shared__ int sm[512];
    int t = threadIdx.x, i = blockIdx.x * 512 + t;
    int v = (i < n) ? deg[i] : 0;
    sm[t] = v; __syncthreads();
    for (int off = 1; off < 512; off <<= 1) {
        int a = (t >= off) ? sm[t - off] : 0;
        __syncthreads();
        sm[t] += a;
        __syncthreads();
    }
    if (i < n) ptr[i] = sm[t] - v;          // exclusive within block
    if (t == 511) bsum[blockIdx.x] = sm[511];
}

__global__ void k_scan2(const int* __restrict__ bsum, int* __restrict__ boff, int nb) {
    __shared__ int sm[512];
    int t = threadIdx.x;
    int v = (t < nb) ? bsum[t] : 0;
    sm[t] = v; __syncthreads();
    for (int off = 1; off < 512; off <<= 1) {
        int a = (t >= off) ? sm[t - off] : 0;
        __syncthreads();
        sm[t] += a;
        __syncthreads();
    }
    if (t < nb) boff[t] = sm[t] - v;
}

__global__ void k_scan3(int* __restrict__ ptr, const int* __restrict__ boff,
                        int n, int nE) {
    int i = blockIdx.x * 512 + threadIdx.x;
    if (i < n) ptr[i] += boff[blockIdx.x];
    if (i == 0) ptr[n] = nE;
}

__global__ __launch_bounds__(256) void k_scatter(const int* __restrict__ ei,
                                                 const unsigned short* __restrict__ rank,
                                                 const int* __restrict__ ptr,
                                                 int* __restrict__ csrc, int nE) {
    int base = blockIdx.x * 1024 + threadIdx.x;
#pragma unroll
    for (int j = 0; j < 4; ++j) {
        int e = base + j * 256;
        if (e < nE) {
            int d = ei[nE + e];
            csrc[ptr[d] + (int)rank[e]] = ei[e];
        }
    }
}

// ---------------- Fused gather1 (+dinv, +b1, +relu) + GEMM2 + dinv ----------------
// One wave per node. Gather: 16 lanes x float4 per row, 4 edge-groups, per-edge
// dinv[src] weight (Y1 is raw xW1). After butterfly, all lanes hold full agg.
// Then h-row staged in LDS, y2 = dinv * (h @ W2) computed with lane=(kgrp,colgrp),
// butterfly-reduced over kgrps. W2 in LDS, padded [64][68] against bank conflicts.

__global__ __launch_bounds__(256) void k_g1mm(const float4* __restrict__ Y1,
                                              const int* __restrict__ ptr,
                                              const int* __restrict__ csrc,
                                              const float* __restrict__ dinv,
                                              const float4* __restrict__ b1_4,
                                              const float4* __restrict__ W2_4,
                                              float4* __restrict__ Y2, int n) {
    __shared__ __align__(16) float sW2[64][68];
    __shared__ float hrow[4][64];
    {
        int t = threadIdx.x;
#pragma unroll
        for (int j = 0; j < 4; ++j) {
            int idx = t + j * 256;               // 0..1023 float4s of W2 [k][c]
            int k = idx >> 4, c4 = idx & 15;
            *(float4*)&sW2[k][c4 << 2] = W2_4[idx];
        }
    }
    int wv = threadIdx.x >> 6, lane = threadIdx.x & 63;
    int q = lane >> 4, f4 = lane & 15;
    int node = blockIdx.x * 4 + wv;
    bool act = node < n;
    float di = 0.f;
    if (act) {
        int s = ptr[node], e = ptr[node + 1];
        float4 acc = make_float4(0.f, 0.f, 0.f, 0.f);
        int k = s + q;
        while (k + 4 < e) {
            int s0 = csrc[k], s1 = csrc[k + 4];
            float d0 = dinv[s0], d1 = dinv[s1];
            float4 v0 = Y1[(size_t)s0 * 16 + f4];
            float4 v1 = Y1[(size_t)s1 * 16 + f4];
            acc.x += v0.x * d0 + v1.x * d1;
            acc.y += v0.y * d0 + v1.y * d1;
            acc.z += v0.z * d0 + v1.z * d1;
            acc.w += v0.w * d0 + v1.w * d1;
            k += 8;
        }
        if (k < e) {
            int s0 = csrc[k];
            float d0 = dinv[s0];
            float4 v0 = Y1[(size_t)s0 * 16 + f4];
            acc.x += v0.x * d0; acc.y += v0.y * d0;
            acc.z += v0.z * d0; acc.w += v0.w * d0;
        }
#pragma unroll
        for (int m = 16; m <= 32; m <<= 1) {
            acc.x += __shfl_xor(acc.x, m);
            acc.y += __shfl_xor(acc.y, m);
            acc.z += __shfl_xor(acc.z, m);
            acc.w += __shfl_xor(acc.w, m);
        }
        di = dinv[node];
        float4 self = Y1[(size_t)node * 16 + f4];  // raw xw1[node]
        float4 b = b1_4[f4];
        // h = relu(di*(acc + di*self) + b1)
        float4 h;
        h.x = fmaxf(fmaf(di, fmaf(di, self.x, acc.x), b.x), 0.f);
        h.y = fmaxf(fmaf(di, fmaf(di, self.y, acc.y), b.y), 0.f);
        h.z = fmaxf(fmaf(di, fmaf(di, self.z, acc.z), b.z), 0.f);
        h.w = fmaxf(fmaf(di, fmaf(di, self.w, acc.w), b.w), 0.f);
        if (q == 0) {
            int c = f4 << 2;
            hrow[wv][c] = h.x; hrow[wv][c + 1] = h.y;
            hrow[wv][c + 2] = h.z; hrow[wv][c + 3] = h.w;
        }
    }
    __syncthreads();
    if (act) {
        float4 p = make_float4(0.f, 0.f, 0.f, 0.f);
        int kb = q << 4, c = f4 << 2;
#pragma unroll
        for (int i = 0; i < 16; ++i) {
            float hv = hrow[wv][kb + i];
            float4 w = *(const float4*)&sW2[kb + i][c];
            p.x = fmaf(hv, w.x, p.x); p.y = fmaf(hv, w.y, p.y);
            p.z = fmaf(hv, w.z, p.z); p.w = fmaf(hv, w.w, p.w);
        }
#pragma unroll
        for (int m = 16; m <= 32; m <<= 1) {
            p.x += __shfl_xor(p.x, m);
            p.y += __shfl_xor(p.y, m);
            p.z += __shfl_xor(p.z, m);
            p.w += __shfl_xor(p.w, m);
        }
        if (q == 0)
            Y2[(size_t)node * 16 + f4] = make_float4(di * p.x, di * p.y,
                                                     di * p.z, di * p.w);
    }
}

// ---------------- Gather2: Y2 is pre-scaled (dinv folded), adds b2 ----------------

__global__ __launch_bounds__(256) void k_gather4(const float4* __restrict__ Yin,
                                                 const int* __restrict__ ptr,
                                                 const int* __restrict__ csrc,
                                                 const float* __restrict__ dinv,
                                                 const float4* __restrict__ bias4,
                                                 float4* __restrict__ out, int n) {
    int node = blockIdx.x * 4 + (threadIdx.x >> 6);
    int lane = threadIdx.x & 63;
    int q  = lane >> 4;
    int f4 = lane & 15;
    if (node >= n) return;
    int s = ptr[node], e = ptr[node + 1];
    float4 acc = make_float4(0.f, 0.f, 0.f, 0.f);
    int k = s + q;
    while (k + 4 < e) {
        int s0 = csrc[k], s1 = csrc[k + 4];
        float4 v0 = Yin[(size_t)s0 * 16 + f4];
        float4 v1 = Yin[(size_t)s1 * 16 + f4];
        acc.x += v0.x + v1.x; acc.y += v0.y + v1.y;
        acc.z += v0.z + v1.z; acc.w += v0.w + v1.w;
        k += 8;
    }
    if (k < e) {
        int s0 = csrc[k];
        float4 v0 = Yin[(size_t)s0 * 16 + f4];
        acc.x += v0.x; acc.y += v0.y; acc.z += v0.z; acc.w += v0.w;
    }
#pragma unroll
    for (int m = 16; m <= 32; m <<= 1) {
        acc.x += __shfl_xor(acc.x, m);
        acc.y += __shfl_xor(acc.y, m);
        acc.z += __shfl_xor(acc.z, m);
        acc.w += __shfl_xor(acc.w, m);
    }
    if (q == 0) {
        float4 self = Yin[(size_t)node * 16 + f4];
        float di = dinv[node];
        float4 b = bias4[f4];
        float4 r;
        r.x = fmaf(di, acc.x + self.x, b.x);
        r.y = fmaf(di, acc.y + self.y, b.y);
        r.z = fmaf(di, acc.z + self.z, b.z);
        r.w = fmaf(di, acc.w + self.w, b.w);
        out[(size_t)node * 16 + f4] = r;
    }
}

// ---------------- Pool (batch sorted) + readout ----------------

__global__ __launch_bounds__(256) void k_pool2(const float* __restrict__ h,
                                               const int* __restrict__ batch,
                                               float* __restrict__ sums,
                                               float* __restrict__ cnt, int n) {
    int wave = blockIdx.x * 4 + (threadIdx.x >> 6);
    int lane = threadIdx.x & 63;
    int start = wave * POOL_CHUNK;
    if (start >= n) return;
    int end = min(start + POOL_CHUNK, n);
    int g = batch[start];
    float acc = 0.f;
    int cl = 0;
    for (int i = start; i < end; ++i) {
        int gi = batch[i];
        if (gi != g) {
            atomicAdd(&sums[g * 64 + lane], acc);
            if (lane == 0) atomicAdd(&cnt[g], (float)cl);
            acc = 0.f; cl = 0; g = gi;
        }
        acc += h[(size_t)i * 64 + lane];
        ++cl;
    }
    atomicAdd(&sums[g * 64 + lane], acc);
    if (lane == 0) atomicAdd(&cnt[g], (float)cl);
}

__global__ void k_final(const float* __restrict__ sums, const float* __restrict__ cnt,
                        const float* __restrict__ Wlin, const float* __restrict__ blin,
                        float* __restrict__ out) {
    int i = blockIdx.x * 128 + threadIdx.x;
    if (i < NGRAPHS * 10) {
        int g = i / 10, c = i % 10;
        float inv = 1.f / fmaxf(cnt[g], 1.f);
        float acc = 0.f;
#pragma unroll
        for (int hh = 0; hh < 64; ++hh)
            acc += sums[g * 64 + hh] * Wlin[hh * 10 + c];
        out[i] = acc * inv + blin[c];
    }
}

// ---------------- launch ----------------

extern "C" void kernel_launch(void* const* d_in, const int* in_sizes, int n_in,
                              void* d_out, int out_size, void* d_ws, size_t ws_size,
                              hipStream_t stream) {
    const float* x     = (const float*)d_in[0];
    const int*   ei    = (const int*)d_in[1];    // int32 per harness contract
    const int*   batch = (const int*)d_in[2];    // int32 per harness contract
    const float* W1    = (const float*)d_in[3];
    const float* b1    = (const float*)d_in[4];
    const float* W2    = (const float*)d_in[5];
    const float* b2    = (const float*)d_in[6];
    const float* Wlin  = (const float*)d_in[7];
    const float* blin  = (const float*)d_in[8];
    float* out = (float*)d_out;

    int n  = in_sizes[0] / NFEAT;   // 100000
    int nE = in_sizes[1] / 2;       // 3200000

    char* ws = (char*)d_ws;
    auto alloc = [&](size_t b) -> void* {
        void* p = (void*)ws;
        ws += (b + 255) & ~(size_t)255;
        return p;
    };
    int*            deg  = (int*)alloc((size_t)n * 4);
    float*          dinv = (float*)alloc((size_t)n * 4);
    int*            ptr  = (int*)alloc((size_t)(n + 1) * 4);
    unsigned short* rank = (unsigned short*)alloc((size_t)nE * 2);
    int*            bsum = (int*)alloc(4096);
    int*            boff = (int*)alloc(4096);
    int*            csrc = (int*)alloc((size_t)nE * 4);
    float*          bufA = (float*)alloc((size_t)n * HID * 4);
    float*          bufB = (float*)alloc((size_t)n * HID * 4);
    float*          sums = (float*)alloc((size_t)NGRAPHS * HID * 4);
    float*          cnt  = (float*)alloc((size_t)NGRAPHS * 4);

    hipMemsetAsync(deg, 0, (size_t)n * 4, stream);
    hipMemsetAsync(sums, 0, (size_t)NGRAPHS * HID * 4, stream);
    hipMemsetAsync(cnt, 0, (size_t)NGRAPHS * 4, stream);

    int nb = (n + 511) / 512;          // 196
    int nGemm  = (n + 63) / 64;        // 1563
    int nCount = (nE + 1023) / 1024;   // 3125
    int grid_f = nGemm + nCount;       // 4688 (mapping: bid%3==0 -> gemm)

    // fused GEMM1 (raw xW1 -> bufA) + degree/rank histogram
    k_gemm1_count<<<grid_f, 256, 0, stream>>>(x, W1, ei, deg, rank, bufA, n, nE);
    k_dinv<<<(n + 255) / 256, 256, 0, stream>>>(deg, dinv, n);
    k_scan1<<<nb, 512, 0, stream>>>(deg, ptr, bsum, n);
    k_scan2<<<1, 512, 0, stream>>>(bsum, boff, nb);
    k_scan3<<<nb, 512, 0, stream>>>(ptr, boff, n, nE);
    k_scatter<<<(nE + 1023) / 1024, 256, 0, stream>>>(ei, rank, ptr, csrc, nE);

    // fused gather1 + GEMM2: bufA (raw xw1) -> bufB (y2 = dinv * h@W2)
    k_g1mm<<<(n + 3) / 4, 256, 0, stream>>>((const float4*)bufA, ptr, csrc, dinv,
                                            (const float4*)b1, (const float4*)W2,
                                            (float4*)bufB, n);
    // gather2: bufB -> bufA (h2 = agg2 + b2)
    k_gather4<<<(n + 3) / 4, 256, 0, stream>>>((const float4*)bufB, ptr, csrc,
                                               dinv, (const float4*)b2,
                                               (float4*)bufA, n);

    int pool_waves = (n + POOL_CHUNK - 1) / POOL_CHUNK;
    k_pool2<<<(pool_waves + 3) / 4, 256, 0, stream>>>(bufA, batch, sums, cnt, n);
    k_final<<<10, 128, 0, stream>>>(sums, cnt, Wlin, blin, out);
}

// Round 7
// 549.517 us; speedup vs baseline: 3.2911x; 1.1616x over previous
//
#include <hip/hip_runtime.h>
#include <hip/hip_bf16.h>

#define NNODES 100000
#define NEDGES 3200000
#define NFEAT 128
#define HID 64
#define NGRAPHS 128
#define POOL_CHUNK 256

#define BSHIFT 9
#define BSIZE 512           // nodes per bucket
#define NBUCK_MAX 256       // >= ceil(100000/512)=196
#define EPB 8192            // edges per histogram/scatter block

// NOTE: harness passes integer inputs as int32 (NOT int64, despite JAX ref dtype).
// CSR build = 2-level bucket counting sort, no global data atomics:
//   kA   : GEMM1 (raw xW1) fused with per-block LDS bucket histograms
//   k_boff: per-bucket exclusive offsets for each scatter block
//   kC   : bucket-scatter packed (src | dlocal<<17) edges (chunk-dense writes)
//   kD   : per-bucket LDS counting sort -> ptr, dinv, csrc

// ---------------- kA: fused GEMM1 + bucket histogram ----------------
// grid = 5*nblkh; bid%5==4 -> hist block h=bid/5; else gemm tile g=(bid/5)*4+bid%5.

__global__ __launch_bounds__(256, 4) void kA_gemm1_hist(
    const float* __restrict__ X, const float* __restrict__ W,
    const int* __restrict__ ei, int* __restrict__ btotal,
    int* __restrict__ blkcnt,
    float* __restrict__ Y, int n, int nE, int nbuck, int nblkh, int nGemm) {
    __shared__ __align__(16) float sXT[64][65];
    __shared__ __align__(16) float sW[64][64];
    __shared__ int cnt[NBUCK_MAX];
    int bid = blockIdx.x;
    int r5 = bid % 5, q5 = bid / 5;
    int t = threadIdx.x;
    if (r5 != 4) {
        int qb = q5 * 4 + r5;
        if (qb >= nGemm) return;
        // ---- GEMM tile: rows [qb*64, qb*64+64), Y = X @ W1 (raw, no dinv)
        int brow = qb * 64;
        int row = t >> 2, c0 = (t & 3) << 4;
        float4 a0 = make_float4(0.f, 0.f, 0.f, 0.f);
        float4 a1 = a0, a2 = a0, a3 = a0;
        for (int kt = 0; kt < NFEAT; kt += 64) {
            const float4* X4 = (const float4*)X;
            const int rs = NFEAT >> 2;
#pragma unroll
            for (int j = 0; j < 4; ++j) {
                int idx = t + j * 256;
                int r = idx >> 4, c4 = idx & 15;
                int gr = brow + r;
                float4 v = make_float4(0.f, 0.f, 0.f, 0.f);
                if (gr < n) v = X4[(size_t)gr * rs + (kt >> 2) + c4];
                int c = c4 << 2;
                sXT[c][r] = v.x; sXT[c + 1][r] = v.y;
                sXT[c + 2][r] = v.z; sXT[c + 3][r] = v.w;
            }
            const float4* W4 = (const float4*)W;
#pragma unroll
            for (int j = 0; j < 4; ++j) {
                int idx = t + j * 256;
                int k = idx >> 4, c4 = idx & 15;
                *(float4*)&sW[k][c4 << 2] = W4[(size_t)(kt + k) * 16 + c4];
            }
            __syncthreads();
#pragma unroll 4
            for (int k = 0; k < 64; ++k) {
                float xv = sXT[k][row];
                float4 w0 = *(const float4*)&sW[k][c0];
                float4 w1 = *(const float4*)&sW[k][c0 + 4];
                float4 w2 = *(const float4*)&sW[k][c0 + 8];
                float4 w3 = *(const float4*)&sW[k][c0 + 12];
                a0.x = fmaf(xv, w0.x, a0.x); a0.y = fmaf(xv, w0.y, a0.y);
                a0.z = fmaf(xv, w0.z, a0.z); a0.w = fmaf(xv, w0.w, a0.w);
                a1.x = fmaf(xv, w1.x, a1.x); a1.y = fmaf(xv, w1.y, a1.y);
                a1.z = fmaf(xv, w1.z, a1.z); a1.w = fmaf(xv, w1.w, a1.w);
                a2.x = fmaf(xv, w2.x, a2.x); a2.y = fmaf(xv, w2.y, a2.y);
                a2.z = fmaf(xv, w2.z, a2.z); a2.w = fmaf(xv, w2.w, a2.w);
                a3.x = fmaf(xv, w3.x, a3.x); a3.y = fmaf(xv, w3.y, a3.y);
                a3.z = fmaf(xv, w3.z, a3.z); a3.w = fmaf(xv, w3.w, a3.w);
            }
            __syncthreads();
        }
        int gr = brow + row;
        if (gr < n) {
            float4* Y4 = (float4*)Y;
            size_t base = (size_t)gr * 16 + (c0 >> 2);
            Y4[base + 0] = a0; Y4[base + 1] = a1;
            Y4[base + 2] = a2; Y4[base + 3] = a3;
        }
    } else {
        // ---- histogram block h: edges [h*EPB, h*EPB+EPB)
        int h = q5;
        for (int i = t; i < nbuck; i += 256) cnt[i] = 0;
        __syncthreads();
        int base = h * EPB;
        int end = min(base + EPB, nE);
        for (int e = base + t; e < end; e += 256) {
            int d = ei[nE + e];
            atomicAdd(&cnt[d >> BSHIFT], 1);
        }
        __syncthreads();
        for (int i = t; i < nbuck; i += 256) {
            int c = cnt[i];
            blkcnt[(size_t)i * nblkh + h] = c;
            if (c) atomicAdd(&btotal[i], c);
        }
    }
}

// ---------------- k_boff: per (bucket, block) exclusive offsets ----------------
// block b: bbase = sum(btotal[0..b-1]); blkoff[b][h] = bbase + excl-scan of blkcnt[b][*]

__global__ __launch_bounds__(256) void k_boff(const int* __restrict__ btotal,
                                              const int* __restrict__ blkcnt,
                                              int* __restrict__ blkoff,
                                              int* __restrict__ bbase_g, int nblkh) {
    __shared__ int vals[256];
    __shared__ int row[512];
    int b = blockIdx.x, t = threadIdx.x;
    vals[t] = (t < b) ? btotal[t] : 0;
    __syncthreads();
    for (int off = 128; off > 0; off >>= 1) {
        if (t < off) vals[t] += vals[t + off];
        __syncthreads();
    }
    int bbase = vals[0];
    for (int i = t; i < nblkh; i += 256) row[i] = blkcnt[(size_t)b * nblkh + i];
    __syncthreads();
    if (t == 0) {
        bbase_g[b] = bbase;
        int run = bbase;
        for (int i = 0; i < nblkh; ++i) { int x = row[i]; row[i] = run; run += x; }
    }
    __syncthreads();
    for (int i = t; i < nblkh; i += 256) blkoff[(size_t)b * nblkh + i] = row[i];
}

// ---------------- kC: bucket-scatter packed edges ----------------

__global__ __launch_bounds__(256) void kC_scatter(const int* __restrict__ ei,
                                                  const int* __restrict__ blkoff,
                                                  int* __restrict__ bucketed,
                                                  int nE, int nbuck, int nblkh) {
    __shared__ int gcur[NBUCK_MAX];
    int h = blockIdx.x, t = threadIdx.x;
    for (int i = t; i < nbuck; i += 256) gcur[i] = blkoff[(size_t)i * nblkh + h];
    __syncthreads();
    int base = h * EPB;
    int end = min(base + EPB, nE);
    for (int e = base + t; e < end; e += 256) {
        int s = ei[e];
        int d = ei[nE + e];
        int b = d >> BSHIFT, dl = d & (BSIZE - 1);
        int pos = atomicAdd(&gcur[b], 1);
        bucketed[pos] = s | (dl << 17);
    }
}

// ---------------- kD: per-bucket LDS counting sort -> ptr, dinv, csrc ----------------

__global__ __launch_bounds__(256) void kD_sort(const int* __restrict__ bucketed,
                                               const int* __restrict__ btotal,
                                               const int* __restrict__ bbase_g,
                                               int* __restrict__ ptr,
                                               float* __restrict__ dinv,
                                               int* __restrict__ csrc,
                                               int n, int nE, int nbuck) {
    __shared__ int hist[BSIZE];
    __shared__ int cur[BSIZE];
    int b = blockIdx.x, t = threadIdx.x;
    int bbase = bbase_g[b];
    int esz = btotal[b];
    int n0 = b << BSHIFT;
    int nn = min(BSIZE, n - n0);
    for (int i = t; i < BSIZE; i += 256) hist[i] = 0;
    __syncthreads();
    for (int k = t; k < esz; k += 256)
        atomicAdd(&hist[bucketed[bbase + k] >> 17], 1);
    __syncthreads();
    for (int i = t; i < nn; i += 256)
        dinv[n0 + i] = 1.0f / sqrtf((float)hist[i] + 1.0f);
    __syncthreads();
    if (t == 0) {   // exclusive scan in place
        int run = 0;
        for (int i = 0; i < nn; ++i) { int x = hist[i]; hist[i] = run; run += x; }
    }
    __syncthreads();
    for (int i = t; i < nn; i += 256) {
        ptr[n0 + i] = bbase + hist[i];
        cur[i] = hist[i];
    }
    if (b == nbuck - 1 && t == 0) ptr[n] = nE;
    __syncthreads();
    for (int k = t; k < esz; k += 256) {
        int p = bucketed[bbase + k];
        int dl = p >> 17, src = p & 0x1FFFF;
        int r = atomicAdd(&cur[dl], 1);
        csrc[bbase + r] = src;
    }
}

// ---------------- Fused gather1 (+dinv, +b1, +relu) + GEMM2 + dinv ----------------

__global__ __launch_bounds__(256) void k_g1mm(const float4* __restrict__ Y1,
                                              const int* __restrict__ ptr,
                                              const int* __restrict__ csrc,
                                              const float* __restrict__ dinv,
                                              const float4* __restrict__ b1_4,
                                              const float4* __restrict__ W2_4,
                                              float4* __restrict__ Y2, int n) {
    __shared__ __align__(16) float sW2[64][68];
    __shared__ float hrow[4][64];
    {
        int t = threadIdx.x;
#pragma unroll
        for (int j = 0; j < 4; ++j) {
            int idx = t + j * 256;               // 0..1023 float4s of W2 [k][c]
            int k = idx >> 4, c4 = idx & 15;
            *(float4*)&sW2[k][c4 << 2] = W2_4[idx];
        }
    }
    int wv = threadIdx.x >> 6, lane = threadIdx.x & 63;
    int q = lane >> 4, f4 = lane & 15;
    int node = blockIdx.x * 4 + wv;
    bool act = node < n;
    float di = 0.f;
    if (act) {
        int s = ptr[node], e = ptr[node + 1];
        float4 acc = make_float4(0.f, 0.f, 0.f, 0.f);
        int k = s + q;
        while (k + 4 < e) {
            int s0 = csrc[k], s1 = csrc[k + 4];
            float d0 = dinv[s0], d1 = dinv[s1];
            float4 v0 = Y1[(size_t)s0 * 16 + f4];
            float4 v1 = Y1[(size_t)s1 * 16 + f4];
            acc.x += v0.x * d0 + v1.x * d1;
            acc.y += v0.y * d0 + v1.y * d1;
            acc.z += v0.z * d0 + v1.z * d1;
            acc.w += v0.w * d0 + v1.w * d1;
            k += 8;
        }
        if (k < e) {
            int s0 = csrc[k];
            float d0 = dinv[s0];
            float4 v0 = Y1[(size_t)s0 * 16 + f4];
            acc.x += v0.x * d0; acc.y += v0.y * d0;
            acc.z += v0.z * d0; acc.w += v0.w * d0;
        }
#pragma unroll
        for (int m = 16; m <= 32; m <<= 1) {
            acc.x += __shfl_xor(acc.x, m);
            acc.y += __shfl_xor(acc.y, m);
            acc.z += __shfl_xor(acc.z, m);
            acc.w += __shfl_xor(acc.w, m);
        }
        di = dinv[node];
        float4 self = Y1[(size_t)node * 16 + f4];  // raw xw1[node]
        float4 b = b1_4[f4];
        float4 h;
        h.x = fmaxf(fmaf(di, fmaf(di, self.x, acc.x), b.x), 0.f);
        h.y = fmaxf(fmaf(di, fmaf(di, self.y, acc.y), b.y), 0.f);
        h.z = fmaxf(fmaf(di, fmaf(di, self.z, acc.z), b.z), 0.f);
        h.w = fmaxf(fmaf(di, fmaf(di, self.w, acc.w), b.w), 0.f);
        if (q == 0) {
            int c = f4 << 2;
            hrow[wv][c] = h.x; hrow[wv][c + 1] = h.y;
            hrow[wv][c + 2] = h.z; hrow[wv][c + 3] = h.w;
        }
    }
    __syncthreads();
    if (act) {
        float4 p = make_float4(0.f, 0.f, 0.f, 0.f);
        int kb = q << 4, c = f4 << 2;
#pragma unroll
        for (int i = 0; i < 16; ++i) {
            float hv = hrow[wv][kb + i];
            float4 w = *(const float4*)&sW2[kb + i][c];
            p.x = fmaf(hv, w.x, p.x); p.y = fmaf(hv, w.y, p.y);
            p.z = fmaf(hv, w.z, p.z); p.w = fmaf(hv, w.w, p.w);
        }
#pragma unroll
        for (int m = 16; m <= 32; m <<= 1) {
            p.x += __shfl_xor(p.x, m);
            p.y += __shfl_xor(p.y, m);
            p.z += __shfl_xor(p.z, m);
            p.w += __shfl_xor(p.w, m);
        }
        if (q == 0)
            Y2[(size_t)node * 16 + f4] = make_float4(di * p.x, di * p.y,
                                                     di * p.z, di * p.w);
    }
}

// ---------------- Gather2: Y2 pre-scaled (dinv folded), adds b2 ----------------

__global__ __launch_bounds__(256) void k_gather4(const float4* __restrict__ Yin,
                                                 const int* __restrict__ ptr,
                                                 const int* __restrict__ csrc,
                                                 const float* __restrict__ dinv,
                                                 const float4* __restrict__ bias4,
                                                 float4* __restrict__ out, int n) {
    int node = blockIdx.x * 4 + (threadIdx.x >> 6);
    int lane = threadIdx.x & 63;
    int q  = lane >> 4;
    int f4 = lane & 15;
    if (node >= n) return;
    int s = ptr[node], e = ptr[node + 1];
    float4 acc = make_float4(0.f, 0.f, 0.f, 0.f);
    int k = s + q;
    while (k + 4 < e) {
        int s0 = csrc[k], s1 = csrc[k + 4];
        float4 v0 = Yin[(size_t)s0 * 16 + f4];
        float4 v1 = Yin[(size_t)s1 * 16 + f4];
        acc.x += v0.x + v1.x; acc.y += v0.y + v1.y;
        acc.z += v0.z + v1.z; acc.w += v0.w + v1.w;
        k += 8;
    }
    if (k < e) {
        int s0 = csrc[k];
        float4 v0 = Yin[(size_t)s0 * 16 + f4];
        acc.x += v0.x; acc.y += v0.y; acc.z += v0.z; acc.w += v0.w;
    }
#pragma unroll
    for (int m = 16; m <= 32; m <<= 1) {
        acc.x += __shfl_xor(acc.x, m);
        acc.y += __shfl_xor(acc.y, m);
        acc.z += __shfl_xor(acc.z, m);
        acc.w += __shfl_xor(acc.w, m);
    }
    if (q == 0) {
        float4 self = Yin[(size_t)node * 16 + f4];
        float di = dinv[node];
        float4 b = bias4[f4];
        float4 r;
        r.x = fmaf(di, acc.x + self.x, b.x);
        r.y = fmaf(di, acc.y + self.y, b.y);
        r.z = fmaf(di, acc.z + self.z, b.z);
        r.w = fmaf(di, acc.w + self.w, b.w);
        out[(size_t)node * 16 + f4] = r;
    }
}

// ---------------- Pool (batch sorted) + readout ----------------

__global__ __launch_bounds__(256) void k_pool2(const float* __restrict__ h,
                                               const int* __restrict__ batch,
                                               float* __restrict__ sums,
                                               float* __restrict__ cnt, int n) {
    int wave = blockIdx.x * 4 + (threadIdx.x >> 6);
    int lane = threadIdx.x & 63;
    int start = wave * POOL_CHUNK;
    if (start >= n) return;
    int end = min(start + POOL_CHUNK, n);
    int g = batch[start];
    float acc = 0.f;
    int cl = 0;
    for (int i = start; i < end; ++i) {
        int gi = batch[i];
        if (gi != g) {
            atomicAdd(&sums[g * 64 + lane], acc);
            if (lane == 0) atomicAdd(&cnt[g], (float)cl);
            acc = 0.f; cl = 0; g = gi;
        }
        acc += h[(size_t)i * 64 + lane];
        ++cl;
    }
    atomicAdd(&sums[g * 64 + lane], acc);
    if (lane == 0) atomicAdd(&cnt[g], (float)cl);
}

__global__ void k_final(const float* __restrict__ sums, const float* __restrict__ cnt,
                        const float* __restrict__ Wlin, const float* __restrict__ blin,
                        float* __restrict__ out) {
    int i = blockIdx.x * 128 + threadIdx.x;
    if (i < NGRAPHS * 10) {
        int g = i / 10, c = i % 10;
        float inv = 1.f / fmaxf(cnt[g], 1.f);
        float acc = 0.f;
#pragma unroll
        for (int hh = 0; hh < 64; ++hh)
            acc += sums[g * 64 + hh] * Wlin[hh * 10 + c];
        out[i] = acc * inv + blin[c];
    }
}

// ---------------- launch ----------------

extern "C" void kernel_launch(void* const* d_in, const int* in_sizes, int n_in,
                              void* d_out, int out_size, void* d_ws, size_t ws_size,
                              hipStream_t stream) {
    const float* x     = (const float*)d_in[0];
    const int*   ei    = (const int*)d_in[1];    // int32 per harness contract
    const int*   batch = (const int*)d_in[2];    // int32 per harness contract
    const float* W1    = (const float*)d_in[3];
    const float* b1    = (const float*)d_in[4];
    const float* W2    = (const float*)d_in[5];
    const float* b2    = (const float*)d_in[6];
    const float* Wlin  = (const float*)d_in[7];
    const float* blin  = (const float*)d_in[8];
    float* out = (float*)d_out;

    int n  = in_sizes[0] / NFEAT;   // 100000
    int nE = in_sizes[1] / 2;       // 3200000

    int nbuck = (n + BSIZE - 1) >> BSHIFT;    // 196
    int nblkh = (nE + EPB - 1) / EPB;         // 391
    int nGemm = (n + 63) / 64;                // 1563

    char* ws = (char*)d_ws;
    auto alloc = [&](size_t b) -> void* {
        void* p = (void*)ws;
        ws += (b + 255) & ~(size_t)255;
        return p;
    };
    float* dinv    = (float*)alloc((size_t)n * 4);
    int*   ptr     = (int*)alloc((size_t)(n + 1) * 4);
    int*   btotal  = (int*)alloc((size_t)nbuck * 4);
    int*   bbase_g = (int*)alloc((size_t)nbuck * 4);
    int*   blkcnt  = (int*)alloc((size_t)nbuck * nblkh * 4);
    int*   blkoff  = (int*)alloc((size_t)nbuck * nblkh * 4);
    int*   bucketed= (int*)alloc((size_t)nE * 4);
    int*   csrc    = (int*)alloc((size_t)nE * 4);
    float* bufA    = (float*)alloc((size_t)n * HID * 4);
    float* bufB    = (float*)alloc((size_t)n * HID * 4);
    float* sums    = (float*)alloc((size_t)NGRAPHS * HID * 4);
    float* cnt     = (float*)alloc((size_t)NGRAPHS * 4);

    hipMemsetAsync(btotal, 0, (size_t)nbuck * 4, stream);
    hipMemsetAsync(sums, 0, (size_t)NGRAPHS * HID * 4, stream);
    hipMemsetAsync(cnt, 0, (size_t)NGRAPHS * 4, stream);

    // CSR build (bucket counting sort) + GEMM1 fused into kA
    kA_gemm1_hist<<<5 * nblkh, 256, 0, stream>>>(x, W1, ei, btotal, blkcnt,
                                                 bufA, n, nE, nbuck, nblkh, nGemm);
    k_boff<<<nbuck, 256, 0, stream>>>(btotal, blkcnt, blkoff, bbase_g, nblkh);
    kC_scatter<<<nblkh, 256, 0, stream>>>(ei, blkoff, bucketed, nE, nbuck, nblkh);
    kD_sort<<<nbuck, 256, 0, stream>>>(bucketed, btotal, bbase_g, ptr, dinv,
                                       csrc, n, nE, nbuck);

    // fused gather1 + GEMM2: bufA (raw xw1) -> bufB (y2 = dinv * h@W2)
    k_g1mm<<<(n + 3) / 4, 256, 0, stream>>>((const float4*)bufA, ptr, csrc, dinv,
                                            (const float4*)b1, (const float4*)W2,
                                            (float4*)bufB, n);
    // gather2: bufB -> bufA (h2 = agg2 + b2)
    k_gather4<<<(n + 3) / 4, 256, 0, stream>>>((const float4*)bufB, ptr, csrc,
                                               dinv, (const float4*)b2,
                                               (float4*)bufA, n);

    int pool_waves = (n + POOL_CHUNK - 1) / POOL_CHUNK;
    k_pool2<<<(pool_waves + 3) / 4, 256, 0, stream>>>(bufA, batch, sums, cnt, n);
    k_final<<<10, 128, 0, stream>>>(sums, cnt, Wlin, blin, out);
}

// Round 8
// 415.229 us; speedup vs baseline: 4.3554x; 1.3234x over previous
//
#include <hip/hip_runtime.h>
#include <hip/hip_bf16.h>

#define NNODES 100000
#define NEDGES 3200000
#define NFEAT 128
#define HID 64
#define NGRAPHS 128

#define BSHIFT 9
#define BSIZE 512           // nodes per bucket
#define NBUCK_MAX 256       // >= ceil(100000/512)=196
#define EPB 8192            // edges per histogram/scatter block
#define GCH 16              // nodes per wave in k_gpool

// NOTE: harness passes integer inputs as int32 (NOT int64, despite JAX ref dtype).
// Pipeline:
//   kA   : GEMM1 (raw xW1) fused with per-block LDS bucket histograms
//   k_boff/kC/kD : 2-level bucket counting sort -> ptr, dinv, csrc (no global atomics)
//   k_cnt/k_ginv/k_wc : per-graph counts, Wc = W2@Wlin, bc = b2@Wlin+blin
//   k_g1mm : gather1 + relu + r = dinv*(h@Wc)  [layer2 GEMM collapsed to 64x16]
//   k_gpool: 64B-row gather + per-graph accumulation (layer2 prop + pool + linear)
//   k_fin2 : out = gsum + bc

// ---------------- kA: fused GEMM1 + bucket histogram ----------------

__global__ __launch_bounds__(256, 4) void kA_gemm1_hist(
    const float* __restrict__ X, const float* __restrict__ W,
    const int* __restrict__ ei, int* __restrict__ btotal,
    int* __restrict__ blkcnt,
    float* __restrict__ Y, int n, int nE, int nbuck, int nblkh, int nGemm) {
    __shared__ __align__(16) float sXT[64][65];
    __shared__ __align__(16) float sW[64][64];
    __shared__ int cnt[NBUCK_MAX];
    int bid = blockIdx.x;
    int r5 = bid % 5, q5 = bid / 5;
    int t = threadIdx.x;
    if (r5 != 4) {
        int qb = q5 * 4 + r5;
        if (qb >= nGemm) return;
        int brow = qb * 64;
        int row = t >> 2, c0 = (t & 3) << 4;
        float4 a0 = make_float4(0.f, 0.f, 0.f, 0.f);
        float4 a1 = a0, a2 = a0, a3 = a0;
        for (int kt = 0; kt < NFEAT; kt += 64) {
            const float4* X4 = (const float4*)X;
            const int rs = NFEAT >> 2;
#pragma unroll
            for (int j = 0; j < 4; ++j) {
                int idx = t + j * 256;
                int r = idx >> 4, c4 = idx & 15;
                int gr = brow + r;
                float4 v = make_float4(0.f, 0.f, 0.f, 0.f);
                if (gr < n) v = X4[(size_t)gr * rs + (kt >> 2) + c4];
                int c = c4 << 2;
                sXT[c][r] = v.x; sXT[c + 1][r] = v.y;
                sXT[c + 2][r] = v.z; sXT[c + 3][r] = v.w;
            }
            const float4* W4 = (const float4*)W;
#pragma unroll
            for (int j = 0; j < 4; ++j) {
                int idx = t + j * 256;
                int k = idx >> 4, c4 = idx & 15;
                *(float4*)&sW[k][c4 << 2] = W4[(size_t)(kt + k) * 16 + c4];
            }
            __syncthreads();
#pragma unroll 4
            for (int k = 0; k < 64; ++k) {
                float xv = sXT[k][row];
                float4 w0 = *(const float4*)&sW[k][c0];
                float4 w1 = *(const float4*)&sW[k][c0 + 4];
                float4 w2 = *(const float4*)&sW[k][c0 + 8];
                float4 w3 = *(const float4*)&sW[k][c0 + 12];
                a0.x = fmaf(xv, w0.x, a0.x); a0.y = fmaf(xv, w0.y, a0.y);
                a0.z = fmaf(xv, w0.z, a0.z); a0.w = fmaf(xv, w0.w, a0.w);
                a1.x = fmaf(xv, w1.x, a1.x); a1.y = fmaf(xv, w1.y, a1.y);
                a1.z = fmaf(xv, w1.z, a1.z); a1.w = fmaf(xv, w1.w, a1.w);
                a2.x = fmaf(xv, w2.x, a2.x); a2.y = fmaf(xv, w2.y, a2.y);
                a2.z = fmaf(xv, w2.z, a2.z); a2.w = fmaf(xv, w2.w, a2.w);
                a3.x = fmaf(xv, w3.x, a3.x); a3.y = fmaf(xv, w3.y, a3.y);
                a3.z = fmaf(xv, w3.z, a3.z); a3.w = fmaf(xv, w3.w, a3.w);
            }
            __syncthreads();
        }
        int gr = brow + row;
        if (gr < n) {
            float4* Y4 = (float4*)Y;
            size_t base = (size_t)gr * 16 + (c0 >> 2);
            Y4[base + 0] = a0; Y4[base + 1] = a1;
            Y4[base + 2] = a2; Y4[base + 3] = a3;
        }
    } else {
        int h = q5;
        for (int i = t; i < nbuck; i += 256) cnt[i] = 0;
        __syncthreads();
        int base = h * EPB;
        int end = min(base + EPB, nE);
        for (int e = base + t; e < end; e += 256) {
            int d = ei[nE + e];
            atomicAdd(&cnt[d >> BSHIFT], 1);
        }
        __syncthreads();
        for (int i = t; i < nbuck; i += 256) {
            int c = cnt[i];
            blkcnt[(size_t)i * nblkh + h] = c;
            if (c) atomicAdd(&btotal[i], c);
        }
    }
}

// ---------------- k_boff ----------------

__global__ __launch_bounds__(256) void k_boff(const int* __restrict__ btotal,
                                              const int* __restrict__ blkcnt,
                                              int* __restrict__ blkoff,
                                              int* __restrict__ bbase_g, int nblkh) {
    __shared__ int vals[256];
    __shared__ int row[512];
    int b = blockIdx.x, t = threadIdx.x;
    vals[t] = (t < b) ? btotal[t] : 0;
    __syncthreads();
    for (int off = 128; off > 0; off >>= 1) {
        if (t < off) vals[t] += vals[t + off];
        __syncthreads();
    }
    int bbase = vals[0];
    for (int i = t; i < nblkh; i += 256) row[i] = blkcnt[(size_t)b * nblkh + i];
    __syncthreads();
    if (t == 0) {
        bbase_g[b] = bbase;
        int run = bbase;
        for (int i = 0; i < nblkh; ++i) { int x = row[i]; row[i] = run; run += x; }
    }
    __syncthreads();
    for (int i = t; i < nblkh; i += 256) blkoff[(size_t)b * nblkh + i] = row[i];
}

// ---------------- kC: bucket-scatter packed edges ----------------

__global__ __launch_bounds__(256) void kC_scatter(const int* __restrict__ ei,
                                                  const int* __restrict__ blkoff,
                                                  int* __restrict__ bucketed,
                                                  int nE, int nbuck, int nblkh) {
    __shared__ int gcur[NBUCK_MAX];
    int h = blockIdx.x, t = threadIdx.x;
    for (int i = t; i < nbuck; i += 256) gcur[i] = blkoff[(size_t)i * nblkh + h];
    __syncthreads();
    int base = h * EPB;
    int end = min(base + EPB, nE);
    for (int e = base + t; e < end; e += 256) {
        int s = ei[e];
        int d = ei[nE + e];
        int b = d >> BSHIFT, dl = d & (BSIZE - 1);
        int pos = atomicAdd(&gcur[b], 1);
        bucketed[pos] = s | (dl << 17);
    }
}

// ---------------- kD: per-bucket LDS counting sort -> ptr, dinv, csrc ----------------

__global__ __launch_bounds__(256) void kD_sort(const int* __restrict__ bucketed,
                                               const int* __restrict__ btotal,
                                               const int* __restrict__ bbase_g,
                                               int* __restrict__ ptr,
                                               float* __restrict__ dinv,
                                               int* __restrict__ csrc,
                                               int n, int nE, int nbuck) {
    __shared__ int hist[BSIZE];
    __shared__ int cur[BSIZE];
    int b = blockIdx.x, t = threadIdx.x;
    int bbase = bbase_g[b];
    int esz = btotal[b];
    int n0 = b << BSHIFT;
    int nn = min(BSIZE, n - n0);
    for (int i = t; i < BSIZE; i += 256) hist[i] = 0;
    __syncthreads();
    for (int k = t; k < esz; k += 256)
        atomicAdd(&hist[bucketed[bbase + k] >> 17], 1);
    __syncthreads();
    for (int i = t; i < nn; i += 256)
        dinv[n0 + i] = 1.0f / sqrtf((float)hist[i] + 1.0f);
    __syncthreads();
    if (t == 0) {
        int run = 0;
        for (int i = 0; i < nn; ++i) { int x = hist[i]; hist[i] = run; run += x; }
    }
    __syncthreads();
    for (int i = t; i < nn; i += 256) {
        ptr[n0 + i] = bbase + hist[i];
        cur[i] = hist[i];
    }
    if (b == nbuck - 1 && t == 0) ptr[n] = nE;
    __syncthreads();
    for (int k = t; k < esz; k += 256) {
        int p = bucketed[bbase + k];
        int dl = p >> 17, src = p & 0x1FFFF;
        int r = atomicAdd(&cur[dl], 1);
        csrc[bbase + r] = src;
    }
}

// ---------------- tiny prep kernels ----------------

__global__ void k_cnt(const int* __restrict__ batch, int* __restrict__ gcnt, int n) {
    __shared__ int h[NGRAPHS];
    int t = threadIdx.x;
    if (t < NGRAPHS) h[t] = 0;
    __syncthreads();
    int base = blockIdx.x * 1024;
    int end = min(base + 1024, n);
    for (int i = base + t; i < end; i += 256) atomicAdd(&h[batch[i]], 1);
    __syncthreads();
    if (t < NGRAPHS && h[t]) atomicAdd(&gcnt[t], h[t]);
}

__global__ void k_ginv(const int* __restrict__ gcnt, float* __restrict__ ginv) {
    int t = threadIdx.x;
    if (t < NGRAPHS) ginv[t] = 1.f / fmaxf((float)gcnt[t], 1.f);
}

// Wc[64][16] = W2 @ Wlin (cols 10..15 zero); bc[16] = b2 @ Wlin + blin
__global__ void k_wc(const float* __restrict__ W2, const float* __restrict__ Wlin,
                     const float* __restrict__ b2, const float* __restrict__ blin,
                     float* __restrict__ Wc, float* __restrict__ bc) {
    int t = threadIdx.x;
    for (int idx = t; idx < 64 * 16; idx += 256) {
        int k = idx >> 4, c = idx & 15;
        float a = 0.f;
        if (c < 10) {
#pragma unroll 8
            for (int m = 0; m < 64; ++m) a = fmaf(W2[k * 64 + m], Wlin[m * 10 + c], a);
        }
        Wc[idx] = a;
    }
    if (t < 16) {
        float a = 0.f;
        if (t < 10) {
            a = blin[t];
            for (int m = 0; m < 64; ++m) a = fmaf(b2[m], Wlin[m * 10 + t], a);
        }
        bc[t] = a;
    }
}

// ---------------- k_g1mm: gather1 + relu + r = dinv*(h@Wc) ----------------

__global__ __launch_bounds__(256) void k_g1mm(const float4* __restrict__ Y1,
                                              const int* __restrict__ ptr,
                                              const int* __restrict__ csrc,
                                              const float* __restrict__ dinv,
                                              const float4* __restrict__ b1_4,
                                              const float* __restrict__ Wc,
                                              float* __restrict__ rbuf, int n) {
    __shared__ float sWc[64][17];
    __shared__ float hrow[4][64];
    {
        int t = threadIdx.x;
#pragma unroll
        for (int j = 0; j < 4; ++j) {
            int idx = t + j * 256;               // 0..1023 of Wc[k][c]
            sWc[idx >> 4][idx & 15] = Wc[idx];
        }
    }
    int wv = threadIdx.x >> 6, lane = threadIdx.x & 63;
    int q = lane >> 4, f4 = lane & 15;
    int node = blockIdx.x * 4 + wv;
    bool act = node < n;
    float di = 0.f;
    if (act) {
        int s = ptr[node], e = ptr[node + 1];
        float4 acc = make_float4(0.f, 0.f, 0.f, 0.f);
        int k = s + q;
        while (k + 4 < e) {
            int s0 = csrc[k], s1 = csrc[k + 4];
            float d0 = dinv[s0], d1 = dinv[s1];
            float4 v0 = Y1[(size_t)s0 * 16 + f4];
            float4 v1 = Y1[(size_t)s1 * 16 + f4];
            acc.x += v0.x * d0 + v1.x * d1;
            acc.y += v0.y * d0 + v1.y * d1;
            acc.z += v0.z * d0 + v1.z * d1;
            acc.w += v0.w * d0 + v1.w * d1;
            k += 8;
        }
        if (k < e) {
            int s0 = csrc[k];
            float d0 = dinv[s0];
            float4 v0 = Y1[(size_t)s0 * 16 + f4];
            acc.x += v0.x * d0; acc.y += v0.y * d0;
            acc.z += v0.z * d0; acc.w += v0.w * d0;
        }
#pragma unroll
        for (int m = 16; m <= 32; m <<= 1) {
            acc.x += __shfl_xor(acc.x, m);
            acc.y += __shfl_xor(acc.y, m);
            acc.z += __shfl_xor(acc.z, m);
            acc.w += __shfl_xor(acc.w, m);
        }
        di = dinv[node];
        float4 self = Y1[(size_t)node * 16 + f4];  // raw xw1[node]
        float4 b = b1_4[f4];
        float4 h;
        h.x = fmaxf(fmaf(di, fmaf(di, self.x, acc.x), b.x), 0.f);
        h.y = fmaxf(fmaf(di, fmaf(di, self.y, acc.y), b.y), 0.f);
        h.z = fmaxf(fmaf(di, fmaf(di, self.z, acc.z), b.z), 0.f);
        h.w = fmaxf(fmaf(di, fmaf(di, self.w, acc.w), b.w), 0.f);
        if (q == 0) {
            int c = f4 << 2;
            hrow[wv][c] = h.x; hrow[wv][c + 1] = h.y;
            hrow[wv][c + 2] = h.z; hrow[wv][c + 3] = h.w;
        }
    }
    __syncthreads();
    if (act) {
        // r[node][c] = di * sum_k h[k]*Wc[k][c];  lane: c = f4, k-range = q*16..+16
        float p = 0.f;
        int kb = q << 4;
#pragma unroll
        for (int i = 0; i < 16; ++i)
            p = fmaf(hrow[wv][kb + i], sWc[kb + i][f4], p);
        p += __shfl_xor(p, 16);
        p += __shfl_xor(p, 32);
        if (lane < 16)
            rbuf[(size_t)node * 16 + lane] = di * p;
    }
}

// ---------------- k_gpool: layer2 prop + mean-pool + Wlin, on 64B rows ----------------
// wave per GCH consecutive nodes; 4-lane quads gather 16 edges concurrently;
// per-graph register accumulation (batch sorted), few atomics.

__global__ __launch_bounds__(256) void k_gpool(const float4* __restrict__ rbuf4,
                                               const int* __restrict__ ptr,
                                               const int* __restrict__ csrc,
                                               const float* __restrict__ dinv,
                                               const int* __restrict__ batch,
                                               const float* __restrict__ ginv,
                                               float* __restrict__ gsum, int n) {
    int wave = blockIdx.x * 4 + (threadIdx.x >> 6);
    int lane = threadIdx.x & 63;
    int quad = lane >> 2, f4 = lane & 3;
    int start = wave * GCH;
    if (start >= n) return;
    int end = min(start + GCH, n);
    int g = batch[start];
    float4 gacc = make_float4(0.f, 0.f, 0.f, 0.f);
    for (int nd = start; nd < end; ++nd) {
        int gn = batch[nd];
        if (gn != g) {
            if (quad == 0) {
                atomicAdd(&gsum[g * 16 + f4 * 4 + 0], gacc.x);
                atomicAdd(&gsum[g * 16 + f4 * 4 + 1], gacc.y);
                atomicAdd(&gsum[g * 16 + f4 * 4 + 2], gacc.z);
                atomicAdd(&gsum[g * 16 + f4 * 4 + 3], gacc.w);
            }
            gacc = make_float4(0.f, 0.f, 0.f, 0.f);
            g = gn;
        }
        int s = ptr[nd], e = ptr[nd + 1];
        float4 acc = make_float4(0.f, 0.f, 0.f, 0.f);
        if (quad == 0) acc = rbuf4[(size_t)nd * 4 + f4];   // self term
        for (int k = s + quad; k < e; k += 16) {
            float4 v = rbuf4[(size_t)csrc[k] * 4 + f4];
            acc.x += v.x; acc.y += v.y; acc.z += v.z; acc.w += v.w;
        }
#pragma unroll
        for (int m = 4; m <= 32; m <<= 1) {
            acc.x += __shfl_xor(acc.x, m);
            acc.y += __shfl_xor(acc.y, m);
            acc.z += __shfl_xor(acc.z, m);
            acc.w += __shfl_xor(acc.w, m);
        }
        float sc = dinv[nd] * ginv[g];
        if (quad == 0) {
            gacc.x = fmaf(sc, acc.x, gacc.x);
            gacc.y = fmaf(sc, acc.y, gacc.y);
            gacc.z = fmaf(sc, acc.z, gacc.z);
            gacc.w = fmaf(sc, acc.w, gacc.w);
        }
    }
    if (quad == 0) {
        atomicAdd(&gsum[g * 16 + f4 * 4 + 0], gacc.x);
        atomicAdd(&gsum[g * 16 + f4 * 4 + 1], gacc.y);
        atomicAdd(&gsum[g * 16 + f4 * 4 + 2], gacc.z);
        atomicAdd(&gsum[g * 16 + f4 * 4 + 3], gacc.w);
    }
}

__global__ void k_fin2(const float* __restrict__ gsum, const float* __restrict__ bc,
                       float* __restrict__ out) {
    int i = blockIdx.x * 256 + threadIdx.x;
    if (i < NGRAPHS * 10) {
        int g = i / 10, c = i - g * 10;
        out[i] = gsum[g * 16 + c] + bc[c];
    }
}

// ---------------- launch ----------------

extern "C" void kernel_launch(void* const* d_in, const int* in_sizes, int n_in,
                              void* d_out, int out_size, void* d_ws, size_t ws_size,
                              hipStream_t stream) {
    const float* x     = (const float*)d_in[0];
    const int*   ei    = (const int*)d_in[1];    // int32 per harness contract
    const int*   batch = (const int*)d_in[2];    // int32 per harness contract
    const float* W1    = (const float*)d_in[3];
    const float* b1    = (const float*)d_in[4];
    const float* W2    = (const float*)d_in[5];
    const float* b2    = (const float*)d_in[6];
    const float* Wlin  = (const float*)d_in[7];
    const float* blin  = (const float*)d_in[8];
    float* out = (float*)d_out;

    int n  = in_sizes[0] / NFEAT;   // 100000
    int nE = in_sizes[1] / 2;       // 3200000

    int nbuck = (n + BSIZE - 1) >> BSHIFT;    // 196
    int nblkh = (nE + EPB - 1) / EPB;         // 391
    int nGemm = (n + 63) / 64;                // 1563

    char* ws = (char*)d_ws;
    auto alloc = [&](size_t b) -> void* {
        void* p = (void*)ws;
        ws += (b + 255) & ~(size_t)255;
        return p;
    };
    float* dinv    = (float*)alloc((size_t)n * 4);
    int*   ptr     = (int*)alloc((size_t)(n + 1) * 4);
    int*   btotal  = (int*)alloc((size_t)nbuck * 4);
    int*   bbase_g = (int*)alloc((size_t)nbuck * 4);
    int*   blkcnt  = (int*)alloc((size_t)nbuck * nblkh * 4);
    int*   blkoff  = (int*)alloc((size_t)nbuck * nblkh * 4);
    int*   bucketed= (int*)alloc((size_t)nE * 4);
    int*   csrc    = (int*)alloc((size_t)nE * 4);
    float* bufA    = (float*)alloc((size_t)n * HID * 4);    // raw xW1
    float* rbuf    = (float*)alloc((size_t)n * 16 * 4);     // r = dinv*(h@Wc), padded
    int*   gcnt    = (int*)alloc((size_t)NGRAPHS * 4);
    float* ginv    = (float*)alloc((size_t)NGRAPHS * 4);
    float* Wc      = (float*)alloc(64 * 16 * 4);
    float* bc      = (float*)alloc(16 * 4);
    float* gsum    = (float*)alloc((size_t)NGRAPHS * 16 * 4);

    hipMemsetAsync(btotal, 0, (size_t)nbuck * 4, stream);
    hipMemsetAsync(gcnt, 0, (size_t)NGRAPHS * 4, stream);
    hipMemsetAsync(gsum, 0, (size_t)NGRAPHS * 16 * 4, stream);

    // CSR build + GEMM1 fused
    kA_gemm1_hist<<<5 * nblkh, 256, 0, stream>>>(x, W1, ei, btotal, blkcnt,
                                                 bufA, n, nE, nbuck, nblkh, nGemm);
    k_boff<<<nbuck, 256, 0, stream>>>(btotal, blkcnt, blkoff, bbase_g, nblkh);
    kC_scatter<<<nblkh, 256, 0, stream>>>(ei, blkoff, bucketed, nE, nbuck, nblkh);
    kD_sort<<<nbuck, 256, 0, stream>>>(bucketed, btotal, bbase_g, ptr, dinv,
                                       csrc, n, nE, nbuck);

    // prep: graph counts, Wc, bc
    k_cnt<<<(n + 1023) / 1024, 256, 0, stream>>>(batch, gcnt, n);
    k_ginv<<<1, NGRAPHS, 0, stream>>>(gcnt, ginv);
    k_wc<<<1, 256, 0, stream>>>(W2, Wlin, b2, blin, Wc, bc);

    // gather1 + relu + collapsed layer2 GEMM: bufA -> rbuf
    k_g1mm<<<(n + 3) / 4, 256, 0, stream>>>((const float4*)bufA, ptr, csrc, dinv,
                                            (const float4*)b1, Wc, rbuf, n);
    // layer2 propagation + mean pool + linear: rbuf -> gsum
    int gwaves = (n + GCH - 1) / GCH;
    k_gpool<<<(gwaves + 3) / 4, 256, 0, stream>>>((const float4*)rbuf, ptr, csrc,
                                                  dinv, batch, ginv, gsum, n);
    k_fin2<<<5, 256, 0, stream>>>(gsum, bc, out);
}

// Round 9
// 411.434 us; speedup vs baseline: 4.3956x; 1.0092x over previous
//
#include <hip/hip_runtime.h>
#include <hip/hip_bf16.h>

#define NNODES 100000
#define NEDGES 3200000
#define NFEAT 128
#define HID 64
#define NGRAPHS 128

#define BSHIFT 9
#define BSIZE 512           // nodes per bucket
#define NBUCK_MAX 256       // >= ceil(100000/512)=196
#define EPB 8192            // edges per histogram/scatter block
#define GCH 16              // nodes per wave in k_gpool

// NOTE: harness passes integer inputs as int32 (NOT int64, despite JAX ref dtype).
// Pipeline:
//   kA   : GEMM1 (raw xW1) fused with per-block LDS bucket histograms
//   k_boff/kC/kD : 2-level bucket counting sort -> ptr, dinv, csrc
//          (kD also pre-scales bufA rows by dinv[src] for the gather)
//   k_cnt/k_ginv/k_wc : per-graph counts, Wc = W2@Wlin, bc = b2@Wlin+blin, zrow
//   k_g1mm : gather1 (prescaled rows) + relu + r = dinv*(h@Wc)
//   k_gpool: 64B-row gather + per-graph accumulation (layer2 prop + pool + linear)
//   k_fin2 : out = gsum + bc

// ---------------- kA: fused GEMM1 + bucket histogram ----------------

__global__ __launch_bounds__(256, 4) void kA_gemm1_hist(
    const float* __restrict__ X, const float* __restrict__ W,
    const int* __restrict__ ei, int* __restrict__ btotal,
    int* __restrict__ blkcnt,
    float* __restrict__ Y, int n, int nE, int nbuck, int nblkh, int nGemm) {
    __shared__ __align__(16) float sXT[64][65];
    __shared__ __align__(16) float sW[64][64];
    __shared__ int cnt[NBUCK_MAX];
    int bid = blockIdx.x;
    int r5 = bid % 5, q5 = bid / 5;
    int t = threadIdx.x;
    if (r5 != 4) {
        int qb = q5 * 4 + r5;
        if (qb >= nGemm) return;
        int brow = qb * 64;
        int row = t >> 2, c0 = (t & 3) << 4;
        float4 a0 = make_float4(0.f, 0.f, 0.f, 0.f);
        float4 a1 = a0, a2 = a0, a3 = a0;
        for (int kt = 0; kt < NFEAT; kt += 64) {
            const float4* X4 = (const float4*)X;
            const int rs = NFEAT >> 2;
#pragma unroll
            for (int j = 0; j < 4; ++j) {
                int idx = t + j * 256;
                int r = idx >> 4, c4 = idx & 15;
                int gr = brow + r;
                float4 v = make_float4(0.f, 0.f, 0.f, 0.f);
                if (gr < n) v = X4[(size_t)gr * rs + (kt >> 2) + c4];
                int c = c4 << 2;
                sXT[c][r] = v.x; sXT[c + 1][r] = v.y;
                sXT[c + 2][r] = v.z; sXT[c + 3][r] = v.w;
            }
            const float4* W4 = (const float4*)W;
#pragma unroll
            for (int j = 0; j < 4; ++j) {
                int idx = t + j * 256;
                int k = idx >> 4, c4 = idx & 15;
                *(float4*)&sW[k][c4 << 2] = W4[(size_t)(kt + k) * 16 + c4];
            }
            __syncthreads();
#pragma unroll 4
            for (int k = 0; k < 64; ++k) {
                float xv = sXT[k][row];
                float4 w0 = *(const float4*)&sW[k][c0];
                float4 w1 = *(const float4*)&sW[k][c0 + 4];
                float4 w2 = *(const float4*)&sW[k][c0 + 8];
                float4 w3 = *(const float4*)&sW[k][c0 + 12];
                a0.x = fmaf(xv, w0.x, a0.x); a0.y = fmaf(xv, w0.y, a0.y);
                a0.z = fmaf(xv, w0.z, a0.z); a0.w = fmaf(xv, w0.w, a0.w);
                a1.x = fmaf(xv, w1.x, a1.x); a1.y = fmaf(xv, w1.y, a1.y);
                a1.z = fmaf(xv, w1.z, a1.z); a1.w = fmaf(xv, w1.w, a1.w);
                a2.x = fmaf(xv, w2.x, a2.x); a2.y = fmaf(xv, w2.y, a2.y);
                a2.z = fmaf(xv, w2.z, a2.z); a2.w = fmaf(xv, w2.w, a2.w);
                a3.x = fmaf(xv, w3.x, a3.x); a3.y = fmaf(xv, w3.y, a3.y);
                a3.z = fmaf(xv, w3.z, a3.z); a3.w = fmaf(xv, w3.w, a3.w);
            }
            __syncthreads();
        }
        int gr = brow + row;
        if (gr < n) {
            float4* Y4 = (float4*)Y;
            size_t base = (size_t)gr * 16 + (c0 >> 2);
            Y4[base + 0] = a0; Y4[base + 1] = a1;
            Y4[base + 2] = a2; Y4[base + 3] = a3;
        }
    } else {
        int h = q5;
        for (int i = t; i < nbuck; i += 256) cnt[i] = 0;
        __syncthreads();
        int base = h * EPB;
        int end = min(base + EPB, nE);
        for (int e = base + t; e < end; e += 256) {
            int d = ei[nE + e];
            atomicAdd(&cnt[d >> BSHIFT], 1);
        }
        __syncthreads();
        for (int i = t; i < nbuck; i += 256) {
            int c = cnt[i];
            blkcnt[(size_t)i * nblkh + h] = c;
            if (c) atomicAdd(&btotal[i], c);
        }
    }
}

// ---------------- k_boff ----------------

__global__ __launch_bounds__(256) void k_boff(const int* __restrict__ btotal,
                                              const int* __restrict__ blkcnt,
                                              int* __restrict__ blkoff,
                                              int* __restrict__ bbase_g, int nblkh) {
    __shared__ int vals[256];
    __shared__ int row[512];
    int b = blockIdx.x, t = threadIdx.x;
    vals[t] = (t < b) ? btotal[t] : 0;
    __syncthreads();
    for (int off = 128; off > 0; off >>= 1) {
        if (t < off) vals[t] += vals[t + off];
        __syncthreads();
    }
    int bbase = vals[0];
    for (int i = t; i < nblkh; i += 256) row[i] = blkcnt[(size_t)b * nblkh + i];
    __syncthreads();
    if (t == 0) {
        bbase_g[b] = bbase;
        int run = bbase;
        for (int i = 0; i < nblkh; ++i) { int x = row[i]; row[i] = run; run += x; }
    }
    __syncthreads();
    for (int i = t; i < nblkh; i += 256) blkoff[(size_t)b * nblkh + i] = row[i];
}

// ---------------- kC: bucket-scatter packed edges ----------------

__global__ __launch_bounds__(256) void kC_scatter(const int* __restrict__ ei,
                                                  const int* __restrict__ blkoff,
                                                  int* __restrict__ bucketed,
                                                  int nE, int nbuck, int nblkh) {
    __shared__ int gcur[NBUCK_MAX];
    int h = blockIdx.x, t = threadIdx.x;
    for (int i = t; i < nbuck; i += 256) gcur[i] = blkoff[(size_t)i * nblkh + h];
    __syncthreads();
    int base = h * EPB;
    int end = min(base + EPB, nE);
    for (int e = base + t; e < end; e += 256) {
        int s = ei[e];
        int d = ei[nE + e];
        int b = d >> BSHIFT, dl = d & (BSIZE - 1);
        int pos = atomicAdd(&gcur[b], 1);
        bucketed[pos] = s | (dl << 17);
    }
}

// ---------------- kD: per-bucket counting sort -> ptr, dinv, csrc ----------------
// Epilogue: pre-scale bufA rows of this bucket's node range by dinv (so the
// gather kernels consume dinv_s * xW1[s] rows directly).

__global__ __launch_bounds__(256) void kD_sort(const int* __restrict__ bucketed,
                                               const int* __restrict__ btotal,
                                               const int* __restrict__ bbase_g,
                                               int* __restrict__ ptr,
                                               float* __restrict__ dinv,
                                               int* __restrict__ csrc,
                                               float* __restrict__ bufA,
                                               int n, int nE, int nbuck) {
    __shared__ int hist[BSIZE];
    __shared__ int cur[BSIZE];
    __shared__ float sdv[BSIZE];
    int b = blockIdx.x, t = threadIdx.x;
    int bbase = bbase_g[b];
    int esz = btotal[b];
    int n0 = b << BSHIFT;
    int nn = min(BSIZE, n - n0);
    for (int i = t; i < BSIZE; i += 256) hist[i] = 0;
    __syncthreads();
    for (int k = t; k < esz; k += 256)
        atomicAdd(&hist[bucketed[bbase + k] >> 17], 1);
    __syncthreads();
    for (int i = t; i < nn; i += 256) {
        float d = 1.0f / sqrtf((float)hist[i] + 1.0f);
        dinv[n0 + i] = d;
        sdv[i] = d;
    }
    __syncthreads();
    if (t == 0) {
        int run = 0;
        for (int i = 0; i < nn; ++i) { int x = hist[i]; hist[i] = run; run += x; }
    }
    __syncthreads();
    for (int i = t; i < nn; i += 256) {
        ptr[n0 + i] = bbase + hist[i];
        cur[i] = hist[i];
    }
    if (b == nbuck - 1 && t == 0) ptr[n] = nE;
    __syncthreads();
    for (int k = t; k < esz; k += 256) {
        int p = bucketed[bbase + k];
        int dl = p >> 17, src = p & 0x1FFFF;
        int r = atomicAdd(&cur[dl], 1);
        csrc[bbase + r] = src;
    }
    // ---- prescale bufA rows for nodes [n0, n0+nn): bufA[s] *= dinv[s]
    float4* A4 = (float4*)bufA;
    size_t base4 = (size_t)n0 * 16;
    for (int i4 = t; i4 < nn * 16; i4 += 256) {
        float sc = sdv[i4 >> 4];
        float4 v = A4[base4 + i4];
        v.x *= sc; v.y *= sc; v.z *= sc; v.w *= sc;
        A4[base4 + i4] = v;
    }
}

// ---------------- tiny prep kernels ----------------

__global__ void k_cnt(const int* __restrict__ batch, int* __restrict__ gcnt, int n) {
    __shared__ int h[NGRAPHS];
    int t = threadIdx.x;
    if (t < NGRAPHS) h[t] = 0;
    __syncthreads();
    int base = blockIdx.x * 1024;
    int end = min(base + 1024, n);
    for (int i = base + t; i < end; i += 256) atomicAdd(&h[batch[i]], 1);
    __syncthreads();
    if (t < NGRAPHS && h[t]) atomicAdd(&gcnt[t], h[t]);
}

__global__ void k_ginv(const int* __restrict__ gcnt, float* __restrict__ ginv) {
    int t = threadIdx.x;
    if (t < NGRAPHS) ginv[t] = 1.f / fmaxf((float)gcnt[t], 1.f);
}

// Wc[64][16] = W2 @ Wlin (cols 10..15 zero); bc[16] = b2 @ Wlin + blin; zrow = 0
__global__ void k_wc(const float* __restrict__ W2, const float* __restrict__ Wlin,
                     const float* __restrict__ b2, const float* __restrict__ blin,
                     float* __restrict__ Wc, float* __restrict__ bc,
                     float* __restrict__ zrow) {
    int t = threadIdx.x;
    for (int idx = t; idx < 64 * 16; idx += 256) {
        int k = idx >> 4, c = idx & 15;
        float a = 0.f;
        if (c < 10) {
#pragma unroll 8
            for (int m = 0; m < 64; ++m) a = fmaf(W2[k * 64 + m], Wlin[m * 10 + c], a);
        }
        Wc[idx] = a;
    }
    if (t < 16) {
        float a = 0.f;
        if (t < 10) {
            a = blin[t];
            for (int m = 0; m < 64; ++m) a = fmaf(b2[m], Wlin[m * 10 + t], a);
        }
        bc[t] = a;
    }
    if (t >= 64 && t < 128) zrow[t - 64] = 0.f;   // 64-float zero row
}

// ---------------- k_g1mm: gather1 (prescaled rows) + relu + r = dinv*(h@Wc) ----
// Rows are dinv_s * xW1[s]. h = relu(dinv_d*(acc + self') + b1) with
// self' = dinv_d*xW1[d] (algebra: dinv_d*(sum_s Y'[s] + dinv_d*y_d)).
// Unroll-4 predicated edge loop: 16 row-loads in flight per wave; invalid
// slots read the cached zero-row. hrow is wave-private -> no mid-kernel sync.

__global__ __launch_bounds__(256) void k_g1mm(const float4* __restrict__ Y1,
                                              const int* __restrict__ ptr,
                                              const int* __restrict__ csrc,
                                              const float* __restrict__ dinv,
                                              const float4* __restrict__ b1_4,
                                              const float* __restrict__ Wc,
                                              const float4* __restrict__ zrow,
                                              float* __restrict__ rbuf, int n) {
    __shared__ float sWc[64][17];
    __shared__ float hrow[4][64];
    int t = threadIdx.x;
#pragma unroll
    for (int j = 0; j < 4; ++j) {
        int idx = t + j * 256;               // 0..1023 of Wc[k][c]
        sWc[idx >> 4][idx & 15] = Wc[idx];
    }
    __syncthreads();
    int wv = t >> 6, lane = t & 63;
    int q = lane >> 4, f4 = lane & 15;
    int node = blockIdx.x * 4 + wv;
    if (node >= n) return;
    int s = ptr[node], e = ptr[node + 1];
    float di = dinv[node];
    float4 self = Y1[(size_t)node * 16 + f4];    // early independent load
    float4 acc = make_float4(0.f, 0.f, 0.f, 0.f);
    for (int k = s + q; k < e; k += 16) {
        int k1 = k + 4, k2 = k + 8, k3 = k + 12;
        int s0 = csrc[k];
        int s1 = (k1 < e) ? csrc[k1] : -1;
        int s2 = (k2 < e) ? csrc[k2] : -1;
        int s3 = (k3 < e) ? csrc[k3] : -1;
        const float4* p0 = Y1 + (size_t)s0 * 16;
        const float4* p1 = (s1 >= 0) ? Y1 + (size_t)s1 * 16 : zrow;
        const float4* p2 = (s2 >= 0) ? Y1 + (size_t)s2 * 16 : zrow;
        const float4* p3 = (s3 >= 0) ? Y1 + (size_t)s3 * 16 : zrow;
        float4 v0 = p0[f4], v1 = p1[f4], v2 = p2[f4], v3 = p3[f4];
        acc.x += (v0.x + v1.x) + (v2.x + v3.x);
        acc.y += (v0.y + v1.y) + (v2.y + v3.y);
        acc.z += (v0.z + v1.z) + (v2.z + v3.z);
        acc.w += (v0.w + v1.w) + (v2.w + v3.w);
    }
#pragma unroll
    for (int m = 16; m <= 32; m <<= 1) {
        acc.x += __shfl_xor(acc.x, m);
        acc.y += __shfl_xor(acc.y, m);
        acc.z += __shfl_xor(acc.z, m);
        acc.w += __shfl_xor(acc.w, m);
    }
    float4 b = b1_4[f4];
    float4 h;
    h.x = fmaxf(fmaf(di, acc.x + self.x, b.x), 0.f);
    h.y = fmaxf(fmaf(di, acc.y + self.y, b.y), 0.f);
    h.z = fmaxf(fmaf(di, acc.z + self.z, b.z), 0.f);
    h.w = fmaxf(fmaf(di, acc.w + self.w, b.w), 0.f);
    if (q == 0) {
        int c = f4 << 2;
        hrow[wv][c] = h.x; hrow[wv][c + 1] = h.y;
        hrow[wv][c + 2] = h.z; hrow[wv][c + 3] = h.w;
    }
    // wave-private LDS: hardware waitcnt orders the write->read within the wave
    float p = 0.f;
    int kb = q << 4;
#pragma unroll
    for (int i = 0; i < 16; ++i)
        p = fmaf(hrow[wv][kb + i], sWc[kb + i][f4], p);
    p += __shfl_xor(p, 16);
    p += __shfl_xor(p, 32);
    if (lane < 16)
        rbuf[(size_t)node * 16 + lane] = di * p;
}

// ---------------- k_gpool: layer2 prop + mean-pool + Wlin, on 64B rows -------
// Unroll-4 predicated: 64 row-loads in flight per wave.

__global__ __launch_bounds__(256) void k_gpool(const float4* __restrict__ rbuf4,
                                               const int* __restrict__ ptr,
                                               const int* __restrict__ csrc,
                                               const float* __restrict__ dinv,
                                               const int* __restrict__ batch,
                                               const float* __restrict__ ginv,
                                               const float4* __restrict__ zrow4,
                                               float* __restrict__ gsum, int n) {
    int wave = blockIdx.x * 4 + (threadIdx.x >> 6);
    int lane = threadIdx.x & 63;
    int quad = lane >> 2, f4 = lane & 3;
    int start = wave * GCH;
    if (start >= n) return;
    int end = min(start + GCH, n);
    int g = batch[start];
    float4 gacc = make_float4(0.f, 0.f, 0.f, 0.f);
    for (int nd = start; nd < end; ++nd) {
        int gn = batch[nd];
        if (gn != g) {
            if (quad == 0) {
                atomicAdd(&gsum[g * 16 + f4 * 4 + 0], gacc.x);
                atomicAdd(&gsum[g * 16 + f4 * 4 + 1], gacc.y);
                atomicAdd(&gsum[g * 16 + f4 * 4 + 2], gacc.z);
                atomicAdd(&gsum[g * 16 + f4 * 4 + 3], gacc.w);
            }
            gacc = make_float4(0.f, 0.f, 0.f, 0.f);
            g = gn;
        }
        int s = ptr[nd], e = ptr[nd + 1];
        float4 acc = make_float4(0.f, 0.f, 0.f, 0.f);
        if (quad == 0) acc = rbuf4[(size_t)nd * 4 + f4];   // self term
        for (int k = s + quad; k < e; k += 64) {
            int k1 = k + 16, k2 = k + 32, k3 = k + 48;
            const float4* p0 = rbuf4 + (size_t)csrc[k] * 4;
            const float4* p1 = (k1 < e) ? rbuf4 + (size_t)csrc[k1] * 4 : zrow4;
            const float4* p2 = (k2 < e) ? rbuf4 + (size_t)csrc[k2] * 4 : zrow4;
            const float4* p3 = (k3 < e) ? rbuf4 + (size_t)csrc[k3] * 4 : zrow4;
            float4 v0 = p0[f4], v1 = p1[f4], v2 = p2[f4], v3 = p3[f4];
            acc.x += (v0.x + v1.x) + (v2.x + v3.x);
            acc.y += (v0.y + v1.y) + (v2.y + v3.y);
            acc.z += (v0.z + v1.z) + (v2.z + v3.z);
            acc.w += (v0.w + v1.w) + (v2.w + v3.w);
        }
#pragma unroll
        for (int m = 4; m <= 32; m <<= 1) {
            acc.x += __shfl_xor(acc.x, m);
            acc.y += __shfl_xor(acc.y, m);
            acc.z += __shfl_xor(acc.z, m);
            acc.w += __shfl_xor(acc.w, m);
        }
        float sc = dinv[nd] * ginv[g];
        if (quad == 0) {
            gacc.x = fmaf(sc, acc.x, gacc.x);
            gacc.y = fmaf(sc, acc.y, gacc.y);
            gacc.z = fmaf(sc, acc.z, gacc.z);
            gacc.w = fmaf(sc, acc.w, gacc.w);
        }
    }
    if (quad == 0) {
        atomicAdd(&gsum[g * 16 + f4 * 4 + 0], gacc.x);
        atomicAdd(&gsum[g * 16 + f4 * 4 + 1], gacc.y);
        atomicAdd(&gsum[g * 16 + f4 * 4 + 2], gacc.z);
        atomicAdd(&gsum[g * 16 + f4 * 4 + 3], gacc.w);
    }
}

__global__ void k_fin2(const float* __restrict__ gsum, const float* __restrict__ bc,
                       float* __restrict__ out) {
    int i = blockIdx.x * 256 + threadIdx.x;
    if (i < NGRAPHS * 10) {
        int g = i / 10, c = i - g * 10;
        out[i] = gsum[g * 16 + c] + bc[c];
    }
}

// ---------------- launch ----------------

extern "C" void kernel_launch(void* const* d_in, const int* in_sizes, int n_in,
                              void* d_out, int out_size, void* d_ws, size_t ws_size,
                              hipStream_t stream) {
    const float* x     = (const float*)d_in[0];
    const int*   ei    = (const int*)d_in[1];    // int32 per harness contract
    const int*   batch = (const int*)d_in[2];    // int32 per harness contract
    const float* W1    = (const float*)d_in[3];
    const float* b1    = (const float*)d_in[4];
    const float* W2    = (const float*)d_in[5];
    const float* b2    = (const float*)d_in[6];
    const float* Wlin  = (const float*)d_in[7];
    const float* blin  = (const float*)d_in[8];
    float* out = (float*)d_out;

    int n  = in_sizes[0] / NFEAT;   // 100000
    int nE = in_sizes[1] / 2;       // 3200000

    int nbuck = (n + BSIZE - 1) >> BSHIFT;    // 196
    int nblkh = (nE + EPB - 1) / EPB;         // 391
    int nGemm = (n + 63) / 64;                // 1563

    char* ws = (char*)d_ws;
    auto alloc = [&](size_t b) -> void* {
        void* p = (void*)ws;
        ws += (b + 255) & ~(size_t)255;
        return p;
    };
    float* dinv    = (float*)alloc((size_t)n * 4);
    int*   ptr     = (int*)alloc((size_t)(n + 1) * 4);
    int*   btotal  = (int*)alloc((size_t)nbuck * 4);
    int*   bbase_g = (int*)alloc((size_t)nbuck * 4);
    int*   blkcnt  = (int*)alloc((size_t)nbuck * nblkh * 4);
    int*   blkoff  = (int*)alloc((size_t)nbuck * nblkh * 4);
    int*   bucketed= (int*)alloc((size_t)nE * 4);
    int*   csrc    = (int*)alloc((size_t)nE * 4);
    float* bufA    = (float*)alloc((size_t)n * HID * 4);    // xW1 (prescaled by kD)
    float* rbuf    = (float*)alloc((size_t)n * 16 * 4);     // r = dinv*(h@Wc)
    int*   gcnt    = (int*)alloc((size_t)NGRAPHS * 4);
    float* ginv    = (float*)alloc((size_t)NGRAPHS * 4);
    float* Wc      = (float*)alloc(64 * 16 * 4);
    float* bc      = (float*)alloc(16 * 4);
    float* zrow    = (float*)alloc(64 * 4);
    float* gsum    = (float*)alloc((size_t)NGRAPHS * 16 * 4);

    hipMemsetAsync(btotal, 0, (size_t)nbuck * 4, stream);
    hipMemsetAsync(gcnt, 0, (size_t)NGRAPHS * 4, stream);
    hipMemsetAsync(gsum, 0, (size_t)NGRAPHS * 16 * 4, stream);

    // CSR build + GEMM1 fused
    kA_gemm1_hist<<<5 * nblkh, 256, 0, stream>>>(x, W1, ei, btotal, blkcnt,
                                                 bufA, n, nE, nbuck, nblkh, nGemm);
    k_boff<<<nbuck, 256, 0, stream>>>(btotal, blkcnt, blkoff, bbase_g, nblkh);
    kC_scatter<<<nblkh, 256, 0, stream>>>(ei, blkoff, bucketed, nE, nbuck, nblkh);
    kD_sort<<<nbuck, 256, 0, stream>>>(bucketed, btotal, bbase_g, ptr, dinv,
                                       csrc, bufA, n, nE, nbuck);

    // prep: graph counts, Wc, bc, zero-row
    k_cnt<<<(n + 1023) / 1024, 256, 0, stream>>>(batch, gcnt, n);
    k_ginv<<<1, NGRAPHS, 0, stream>>>(gcnt, ginv);
    k_wc<<<1, 256, 0, stream>>>(W2, Wlin, b2, blin, Wc, bc, zrow);

    // gather1 + relu + collapsed layer2 GEMM: bufA -> rbuf
    k_g1mm<<<(n + 3) / 4, 256, 0, stream>>>((const float4*)bufA, ptr, csrc, dinv,
                                            (const float4*)b1, Wc,
                                            (const float4*)zrow, rbuf, n);
    // layer2 propagation + mean pool + linear: rbuf -> gsum
    int gwaves = (n + GCH - 1) / GCH;
    k_gpool<<<(gwaves + 3) / 4, 256, 0, stream>>>((const float4*)rbuf, ptr, csrc,
                                                  dinv, batch, ginv,
                                                  (const float4*)zrow, gsum, n);
    k_fin2<<<5, 256, 0, stream>>>(gsum, bc, out);
}

// Round 11
// 369.743 us; speedup vs baseline: 4.8912x; 1.1128x over previous
//
#include <hip/hip_runtime.h>
#include <hip/hip_bf16.h>

#define NNODES 100000
#define NEDGES 3200000
#define NFEAT 128
#define HID 64
#define NGRAPHS 128

#define BSHIFT 9
#define BSIZE 512           // nodes per bucket
#define NBUCK_MAX 256       // >= ceil(100000/512)=196
#define EPB 8192            // edges per histogram/scatter block
#define GCH 16              // nodes per wave in k_gpool

// NOTE: harness passes integer inputs as int32 (NOT int64, despite JAX ref dtype).
// Gathered operands (bufA rows = dinv*xW1, rbuf rows = r) are stored BF16 to
// halve L2-miss-path bytes; all accumulation stays fp32.

__device__ __forceinline__ float bf2f(unsigned int s) {
    return __uint_as_float(s << 16);
}
__device__ __forceinline__ unsigned int f2bf(float f) {   // RNE
    unsigned int u = __float_as_uint(f);
    return (u + 0x7FFFu + ((u >> 16) & 1u)) >> 16;
}
__device__ __forceinline__ float4 unpack8lo(uint2 v) {    // 4 bf16 -> float4
    return make_float4(bf2f(v.x & 0xFFFFu), bf2f(v.x >> 16),
                       bf2f(v.y & 0xFFFFu), bf2f(v.y >> 16));
}

// ---------------- kA: fused GEMM1 (bf16 out) + bucket histogram ----------------

__global__ __launch_bounds__(256, 4) void kA_gemm1_hist(
    const float* __restrict__ X, const float* __restrict__ W,
    const int* __restrict__ ei, int* __restrict__ btotal,
    int* __restrict__ blkcnt,
    unsigned short* __restrict__ Y, int n, int nE, int nbuck, int nblkh, int nGemm) {
    __shared__ __align__(16) float sXT[64][65];
    __shared__ __align__(16) float sW[64][64];
    __shared__ int cnt[NBUCK_MAX];
    int bid = blockIdx.x;
    int r5 = bid % 5, q5 = bid / 5;
    int t = threadIdx.x;
    if (r5 != 4) {
        int qb = q5 * 4 + r5;
        if (qb >= nGemm) return;
        int brow = qb * 64;
        int row = t >> 2, c0 = (t & 3) << 4;
        float4 a0 = make_float4(0.f, 0.f, 0.f, 0.f);
        float4 a1 = a0, a2 = a0, a3 = a0;
        for (int kt = 0; kt < NFEAT; kt += 64) {
            const float4* X4 = (const float4*)X;
            const int rs = NFEAT >> 2;
#pragma unroll
            for (int j = 0; j < 4; ++j) {
                int idx = t + j * 256;
                int r = idx >> 4, c4 = idx & 15;
                int gr = brow + r;
                float4 v = make_float4(0.f, 0.f, 0.f, 0.f);
                if (gr < n) v = X4[(size_t)gr * rs + (kt >> 2) + c4];
                int c = c4 << 2;
                sXT[c][r] = v.x; sXT[c + 1][r] = v.y;
                sXT[c + 2][r] = v.z; sXT[c + 3][r] = v.w;
            }
            const float4* W4 = (const float4*)W;
#pragma unroll
            for (int j = 0; j < 4; ++j) {
                int idx = t + j * 256;
                int k = idx >> 4, c4 = idx & 15;
                *(float4*)&sW[k][c4 << 2] = W4[(size_t)(kt + k) * 16 + c4];
            }
            __syncthreads();
#pragma unroll 4
            for (int k = 0; k < 64; ++k) {
                float xv = sXT[k][row];
                float4 w0 = *(const float4*)&sW[k][c0];
                float4 w1 = *(const float4*)&sW[k][c0 + 4];
                float4 w2 = *(const float4*)&sW[k][c0 + 8];
                float4 w3 = *(const float4*)&sW[k][c0 + 12];
                a0.x = fmaf(xv, w0.x, a0.x); a0.y = fmaf(xv, w0.y, a0.y);
                a0.z = fmaf(xv, w0.z, a0.z); a0.w = fmaf(xv, w0.w, a0.w);
                a1.x = fmaf(xv, w1.x, a1.x); a1.y = fmaf(xv, w1.y, a1.y);
                a1.z = fmaf(xv, w1.z, a1.z); a1.w = fmaf(xv, w1.w, a1.w);
                a2.x = fmaf(xv, w2.x, a2.x); a2.y = fmaf(xv, w2.y, a2.y);
                a2.z = fmaf(xv, w2.z, a2.z); a2.w = fmaf(xv, w2.w, a2.w);
                a3.x = fmaf(xv, w3.x, a3.x); a3.y = fmaf(xv, w3.y, a3.y);
                a3.z = fmaf(xv, w3.z, a3.z); a3.w = fmaf(xv, w3.w, a3.w);
            }
            __syncthreads();
        }
        int gr = brow + row;
        if (gr < n) {
            float vv[16] = {a0.x, a0.y, a0.z, a0.w, a1.x, a1.y, a1.z, a1.w,
                            a2.x, a2.y, a2.z, a2.w, a3.x, a3.y, a3.z, a3.w};
            unsigned int pk[8];
#pragma unroll
            for (int i = 0; i < 8; ++i)
                pk[i] = f2bf(vv[2 * i]) | (f2bf(vv[2 * i + 1]) << 16);
            unsigned short* Yr = Y + (size_t)gr * 64 + c0;   // 32B aligned
            ((uint4*)Yr)[0] = make_uint4(pk[0], pk[1], pk[2], pk[3]);
            ((uint4*)Yr)[1] = make_uint4(pk[4], pk[5], pk[6], pk[7]);
        }
    } else {
        int h = q5;
        for (int i = t; i < nbuck; i += 256) cnt[i] = 0;
        __syncthreads();
        int base = h * EPB;
        int end = min(base + EPB, nE);
        for (int e = base + t; e < end; e += 256) {
            int d = ei[nE + e];
            atomicAdd(&cnt[d >> BSHIFT], 1);
        }
        __syncthreads();
        for (int i = t; i < nbuck; i += 256) {
            int c = cnt[i];
            blkcnt[(size_t)i * nblkh + h] = c;
            if (c) atomicAdd(&btotal[i], c);
        }
    }
}

// ---------------- k_boff ----------------

__global__ __launch_bounds__(256) void k_boff(const int* __restrict__ btotal,
                                              const int* __restrict__ blkcnt,
                                              int* __restrict__ blkoff,
                                              int* __restrict__ bbase_g, int nblkh) {
    __shared__ int vals[256];
    __shared__ int row[512];
    int b = blockIdx.x, t = threadIdx.x;
    vals[t] = (t < b) ? btotal[t] : 0;
    __syncthreads();
    for (int off = 128; off > 0; off >>= 1) {
        if (t < off) vals[t] += vals[t + off];
        __syncthreads();
    }
    int bbase = vals[0];
    for (int i = t; i < nblkh; i += 256) row[i] = blkcnt[(size_t)b * nblkh + i];
    __syncthreads();
    if (t == 0) {
        bbase_g[b] = bbase;
        int run = bbase;
        for (int i = 0; i < nblkh; ++i) { int x = row[i]; row[i] = run; run += x; }
    }
    __syncthreads();
    for (int i = t; i < nblkh; i += 256) blkoff[(size_t)b * nblkh + i] = row[i];
}

// ---------------- kC: bucket-scatter packed edges ----------------

__global__ __launch_bounds__(256) void kC_scatter(const int* __restrict__ ei,
                                                  const int* __restrict__ blkoff,
                                                  int* __restrict__ bucketed,
                                                  int nE, int nbuck, int nblkh) {
    __shared__ int gcur[NBUCK_MAX];
    int h = blockIdx.x, t = threadIdx.x;
    for (int i = t; i < nbuck; i += 256) gcur[i] = blkoff[(size_t)i * nblkh + h];
    __syncthreads();
    int base = h * EPB;
    int end = min(base + EPB, nE);
    for (int e = base + t; e < end; e += 256) {
        int s = ei[e];
        int d = ei[nE + e];
        int b = d >> BSHIFT, dl = d & (BSIZE - 1);
        int pos = atomicAdd(&gcur[b], 1);
        bucketed[pos] = s | (dl << 17);
    }
}

// ---------------- kD: per-bucket counting sort + bf16 prescale ----------------

__global__ __launch_bounds__(256) void kD_sort(const int* __restrict__ bucketed,
                                               const int* __restrict__ btotal,
                                               const int* __restrict__ bbase_g,
                                               int* __restrict__ ptr,
                                               float* __restrict__ dinv,
                                               int* __restrict__ csrc,
                                               unsigned short* __restrict__ bufA,
                                               int n, int nE, int nbuck) {
    __shared__ int hist[BSIZE];
    __shared__ int cur[BSIZE];
    __shared__ float sdv[BSIZE];
    int b = blockIdx.x, t = threadIdx.x;
    int bbase = bbase_g[b];
    int esz = btotal[b];
    int n0 = b << BSHIFT;
    int nn = min(BSIZE, n - n0);
    for (int i = t; i < BSIZE; i += 256) hist[i] = 0;
    __syncthreads();
    for (int k = t; k < esz; k += 256)
        atomicAdd(&hist[bucketed[bbase + k] >> 17], 1);
    __syncthreads();
    for (int i = t; i < nn; i += 256) {
        float d = 1.0f / sqrtf((float)hist[i] + 1.0f);
        dinv[n0 + i] = d;
        sdv[i] = d;
    }
    __syncthreads();
    if (t == 0) {
        int run = 0;
        for (int i = 0; i < nn; ++i) { int x = hist[i]; hist[i] = run; run += x; }
    }
    __syncthreads();
    for (int i = t; i < nn; i += 256) {
        ptr[n0 + i] = bbase + hist[i];
        cur[i] = hist[i];
    }
    if (b == nbuck - 1 && t == 0) ptr[n] = nE;
    __syncthreads();
    for (int k = t; k < esz; k += 256) {
        int p = bucketed[bbase + k];
        int dl = p >> 17, src = p & 0x1FFFF;
        int r = atomicAdd(&cur[dl], 1);
        csrc[bbase + r] = src;
    }
    // ---- prescale bf16 rows for nodes [n0, n0+nn): bufA[s] *= dinv[s]
    uint4* A4 = (uint4*)bufA;                 // 8 uint4 chunks per 128B row
    size_t base4 = (size_t)n0 * 8;
    for (int c = t; c < nn * 8; c += 256) {
        float sc = sdv[c >> 3];
        uint4 v = A4[base4 + c];
        uint4 o;
        o.x = f2bf(bf2f(v.x & 0xFFFFu) * sc) | (f2bf(bf2f(v.x >> 16) * sc) << 16);
        o.y = f2bf(bf2f(v.y & 0xFFFFu) * sc) | (f2bf(bf2f(v.y >> 16) * sc) << 16);
        o.z = f2bf(bf2f(v.z & 0xFFFFu) * sc) | (f2bf(bf2f(v.z >> 16) * sc) << 16);
        o.w = f2bf(bf2f(v.w & 0xFFFFu) * sc) | (f2bf(bf2f(v.w >> 16) * sc) << 16);
        A4[base4 + c] = o;
    }
}

// ---------------- tiny prep kernels ----------------

__global__ void k_cnt(const int* __restrict__ batch, int* __restrict__ gcnt, int n) {
    __shared__ int h[NGRAPHS];
    int t = threadIdx.x;
    if (t < NGRAPHS) h[t] = 0;
    __syncthreads();
    int base = blockIdx.x * 1024;
    int end = min(base + 1024, n);
    for (int i = base + t; i < end; i += 256) atomicAdd(&h[batch[i]], 1);
    __syncthreads();
    if (t < NGRAPHS && h[t]) atomicAdd(&gcnt[t], h[t]);
}

__global__ void k_ginv(const int* __restrict__ gcnt, float* __restrict__ ginv) {
    int t = threadIdx.x;
    if (t < NGRAPHS) ginv[t] = 1.f / fmaxf((float)gcnt[t], 1.f);
}

// Wc[64][16] = W2 @ Wlin (cols 10..15 zero); bc[16] = b2 @ Wlin + blin
__global__ void k_wc(const float* __restrict__ W2, const float* __restrict__ Wlin,
                     const float* __restrict__ b2, const float* __restrict__ blin,
                     float* __restrict__ Wc, float* __restrict__ bc) {
    int t = threadIdx.x;
    for (int idx = t; idx < 64 * 16; idx += 256) {
        int k = idx >> 4, c = idx & 15;
        float a = 0.f;
        if (c < 10) {
#pragma unroll 8
            for (int m = 0; m < 64; ++m) a = fmaf(W2[k * 64 + m], Wlin[m * 10 + c], a);
        }
        Wc[idx] = a;
    }
    if (t < 16) {
        float a = 0.f;
        if (t < 10) {
            a = blin[t];
            for (int m = 0; m < 64; ++m) a = fmaf(b2[m], Wlin[m * 10 + t], a);
        }
        bc[t] = a;
    }
}

// ---------------- k_g1mm: bf16 gather1 + relu + r = dinv*(h@Wc) -> bf16 ------

__global__ __launch_bounds__(256) void k_g1mm(const unsigned short* __restrict__ Y1,
                                              const int* __restrict__ ptr,
                                              const int* __restrict__ csrc,
                                              const float* __restrict__ dinv,
                                              const float4* __restrict__ b1_4,
                                              const float* __restrict__ Wc,
                                              const unsigned short* __restrict__ zrow,
                                              unsigned short* __restrict__ rbuf, int n) {
    __shared__ float sWc[64][17];
    __shared__ float hrow[4][64];
    int t = threadIdx.x;
#pragma unroll
    for (int j = 0; j < 4; ++j) {
        int idx = t + j * 256;
        sWc[idx >> 4][idx & 15] = Wc[idx];
    }
    __syncthreads();
    int wv = t >> 6, lane = t & 63;
    int q = lane >> 4, f4 = lane & 15;
    int node = blockIdx.x * 4 + wv;
    if (node >= n) return;
    int s = ptr[node], e = ptr[node + 1];
    float di = dinv[node];
    uint2 selfb = *((const uint2*)(Y1 + (size_t)node * 64) + f4);
    const uint2* zp = (const uint2*)zrow + f4;
    float4 acc = make_float4(0.f, 0.f, 0.f, 0.f);
    for (int k = s + q; k < e; k += 16) {
        int k1 = k + 4, k2 = k + 8, k3 = k + 12;
        int s0 = csrc[k];
        int s1 = (k1 < e) ? csrc[k1] : -1;
        int s2 = (k2 < e) ? csrc[k2] : -1;
        int s3 = (k3 < e) ? csrc[k3] : -1;
        const uint2* p0 = (const uint2*)(Y1 + (size_t)s0 * 64) + f4;
        const uint2* p1 = (s1 >= 0) ? (const uint2*)(Y1 + (size_t)s1 * 64) + f4 : zp;
        const uint2* p2 = (s2 >= 0) ? (const uint2*)(Y1 + (size_t)s2 * 64) + f4 : zp;
        const uint2* p3 = (s3 >= 0) ? (const uint2*)(Y1 + (size_t)s3 * 64) + f4 : zp;
        float4 v0 = unpack8lo(*p0);
        float4 v1 = unpack8lo(*p1);
        float4 v2 = unpack8lo(*p2);
        float4 v3 = unpack8lo(*p3);
        acc.x += (v0.x + v1.x) + (v2.x + v3.x);
        acc.y += (v0.y + v1.y) + (v2.y + v3.y);
        acc.z += (v0.z + v1.z) + (v2.z + v3.z);
        acc.w += (v0.w + v1.w) + (v2.w + v3.w);
    }
#pragma unroll
    for (int m = 16; m <= 32; m <<= 1) {
        acc.x += __shfl_xor(acc.x, m);
        acc.y += __shfl_xor(acc.y, m);
        acc.z += __shfl_xor(acc.z, m);
        acc.w += __shfl_xor(acc.w, m);
    }
    float4 self = unpack8lo(selfb);
    float4 b = b1_4[f4];
    float4 h;
    h.x = fmaxf(fmaf(di, acc.x + self.x, b.x), 0.f);
    h.y = fmaxf(fmaf(di, acc.y + self.y, b.y), 0.f);
    h.z = fmaxf(fmaf(di, acc.z + self.z, b.z), 0.f);
    h.w = fmaxf(fmaf(di, acc.w + self.w, b.w), 0.f);
    if (q == 0) {
        int c = f4 << 2;
        hrow[wv][c] = h.x; hrow[wv][c + 1] = h.y;
        hrow[wv][c + 2] = h.z; hrow[wv][c + 3] = h.w;
    }
    float p = 0.f;
    int kb = q << 4;
#pragma unroll
    for (int i = 0; i < 16; ++i)
        p = fmaf(hrow[wv][kb + i], sWc[kb + i][f4], p);
    p += __shfl_xor(p, 16);
    p += __shfl_xor(p, 32);
    if (lane < 16)
        rbuf[(size_t)node * 16 + lane] = (unsigned short)f2bf(di * p);
}

// ---------------- k_gpool: bf16 32B-row gather + per-graph accumulation ------

__global__ __launch_bounds__(256) void k_gpool(const unsigned short* __restrict__ rb,
                                               const int* __restrict__ ptr,
                                               const int* __restrict__ csrc,
                                               const float* __restrict__ dinv,
                                               const int* __restrict__ batch,
                                               const float* __restrict__ ginv,
                                               const unsigned short* __restrict__ zrow,
                                               float* __restrict__ gsum, int n) {
    int wave = blockIdx.x * 4 + (threadIdx.x >> 6);
    int lane = threadIdx.x & 63;
    int quad = lane >> 2, f4 = lane & 3;   // 16 quads x 8B
    int start = wave * GCH;
    if (start >= n) return;
    int end = min(start + GCH, n);
    int g = batch[start];
    const uint2* zp = (const uint2*)zrow + f4;
    float4 gacc = make_float4(0.f, 0.f, 0.f, 0.f);
    for (int nd = start; nd < end; ++nd) {
        int gn = batch[nd];
        if (gn != g) {
            if (quad == 0) {
                atomicAdd(&gsum[g * 16 + f4 * 4 + 0], gacc.x);
                atomicAdd(&gsum[g * 16 + f4 * 4 + 1], gacc.y);
                atomicAdd(&gsum[g * 16 + f4 * 4 + 2], gacc.z);
                atomicAdd(&gsum[g * 16 + f4 * 4 + 3], gacc.w);
            }
            gacc = make_float4(0.f, 0.f, 0.f, 0.f);
            g = gn;
        }
        int s = ptr[nd], e = ptr[nd + 1];
        float4 acc = make_float4(0.f, 0.f, 0.f, 0.f);
        if (quad == 0)
            acc = unpack8lo(*((const uint2*)(rb + (size_t)nd * 16) + f4));  // self
        for (int k = s + quad; k < e; k += 64) {
            int k1 = k + 16, k2 = k + 32, k3 = k + 48;
            const uint2* p0 = (const uint2*)(rb + (size_t)csrc[k] * 16) + f4;
            const uint2* p1 = (k1 < e) ? (const uint2*)(rb + (size_t)csrc[k1] * 16) + f4 : zp;
            const uint2* p2 = (k2 < e) ? (const uint2*)(rb + (size_t)csrc[k2] * 16) + f4 : zp;
            const uint2* p3 = (k3 < e) ? (const uint2*)(rb + (size_t)csrc[k3] * 16) + f4 : zp;
            float4 v0 = unpack8lo(*p0);
            float4 v1 = unpack8lo(*p1);
            float4 v2 = unpack8lo(*p2);
            float4 v3 = unpack8lo(*p3);
            acc.x += (v0.x + v1.x) + (v2.x + v3.x);
            acc.y += (v0.y + v1.y) + (v2.y + v3.y);
            acc.z += (v0.z + v1.z) + (v2.z + v3.z);
            acc.w += (v0.w + v1.w) + (v2.w + v3.w);
        }
#pragma unroll
        for (int m = 4; m <= 32; m <<= 1) {
            acc.x += __shfl_xor(acc.x, m);
            acc.y += __shfl_xor(acc.y, m);
            acc.z += __shfl_xor(acc.z, m);
            acc.w += __shfl_xor(acc.w, m);
        }
        float sc = dinv[nd] * ginv[g];
        if (quad == 0) {
            gacc.x = fmaf(sc, acc.x, gacc.x);
            gacc.y = fmaf(sc, acc.y, gacc.y);
            gacc.z = fmaf(sc, acc.z, gacc.z);
            gacc.w = fmaf(sc, acc.w, gacc.w);
        }
    }
    if (quad == 0) {
        atomicAdd(&gsum[g * 16 + f4 * 4 + 0], gacc.x);
        atomicAdd(&gsum[g * 16 + f4 * 4 + 1], gacc.y);
        atomicAdd(&gsum[g * 16 + f4 * 4 + 2], gacc.z);
        atomicAdd(&gsum[g * 16 + f4 * 4 + 3], gacc.w);
    }
}

__global__ void k_fin2(const float* __restrict__ gsum, const float* __restrict__ bc,
                       float* __restrict__ out) {
    int i = blockIdx.x * 256 + threadIdx.x;
    if (i < NGRAPHS * 10) {
        int g = i / 10, c = i - g * 10;
        out[i] = gsum[g * 16 + c] + bc[c];
    }
}

// ---------------- launch ----------------

extern "C" void kernel_launch(void* const* d_in, const int* in_sizes, int n_in,
                              void* d_out, int out_size, void* d_ws, size_t ws_size,
                              hipStream_t stream) {
    const float* x     = (const float*)d_in[0];
    const int*   ei    = (const int*)d_in[1];    // int32 per harness contract
    const int*   batch = (const int*)d_in[2];    // int32 per harness contract
    const float* W1    = (const float*)d_in[3];
    const float* b1    = (const float*)d_in[4];
    const float* W2    = (const float*)d_in[5];
    const float* b2    = (const float*)d_in[6];
    const float* Wlin  = (const float*)d_in[7];
    const float* blin  = (const float*)d_in[8];
    float* out = (float*)d_out;

    int n  = in_sizes[0] / NFEAT;   // 100000
    int nE = in_sizes[1] / 2;       // 3200000

    int nbuck = (n + BSIZE - 1) >> BSHIFT;    // 196
    int nblkh = (nE + EPB - 1) / EPB;         // 391
    int nGemm = (n + 63) / 64;                // 1563

    char* ws = (char*)d_ws;
    auto alloc = [&](size_t b) -> void* {
        void* p = (void*)ws;
        ws += (b + 255) & ~(size_t)255;
        return p;
    };
    float*          dinv    = (float*)alloc((size_t)n * 4);
    int*            ptr     = (int*)alloc((size_t)(n + 1) * 4);
    int*            btotal  = (int*)alloc((size_t)nbuck * 4);
    int*            bbase_g = (int*)alloc((size_t)nbuck * 4);
    int*            blkcnt  = (int*)alloc((size_t)nbuck * nblkh * 4);
    int*            blkoff  = (int*)alloc((size_t)nbuck * nblkh * 4);
    int*            bucketed= (int*)alloc((size_t)nE * 4);
    int*            csrc    = (int*)alloc((size_t)nE * 4);
    unsigned short* bufA    = (unsigned short*)alloc((size_t)n * HID * 2);  // bf16 dinv*xW1
    unsigned short* rbuf    = (unsigned short*)alloc((size_t)n * 16 * 2);   // bf16 r
    int*            gcnt    = (int*)alloc((size_t)NGRAPHS * 4);
    float*          ginv    = (float*)alloc((size_t)NGRAPHS * 4);
    float*          Wc      = (float*)alloc(64 * 16 * 4);
    float*          bc      = (float*)alloc(16 * 4);
    unsigned short* zrow    = (unsigned short*)alloc(64 * 2);               // 128B zeros
    float*          gsum    = (float*)alloc((size_t)NGRAPHS * 16 * 4);

    hipMemsetAsync(btotal, 0, (size_t)nbuck * 4, stream);
    hipMemsetAsync(gcnt, 0, (size_t)NGRAPHS * 4, stream);
    hipMemsetAsync(gsum, 0, (size_t)NGRAPHS * 16 * 4, stream);
    hipMemsetAsync(zrow, 0, 64 * 2, stream);

    // CSR build + GEMM1 fused
    kA_gemm1_hist<<<5 * nblkh, 256, 0, stream>>>(x, W1, ei, btotal, blkcnt,
                                                 bufA, n, nE, nbuck, nblkh, nGemm);
    k_boff<<<nbuck, 256, 0, stream>>>(btotal, blkcnt, blkoff, bbase_g, nblkh);
    kC_scatter<<<nblkh, 256, 0, stream>>>(ei, blkoff, bucketed, nE, nbuck, nblkh);
    kD_sort<<<nbuck, 256, 0, stream>>>(bucketed, btotal, bbase_g, ptr, dinv,
                                       csrc, bufA, n, nE, nbuck);

    // prep: graph counts, Wc, bc
    k_cnt<<<(n + 1023) / 1024, 256, 0, stream>>>(batch, gcnt, n);
    k_ginv<<<1, NGRAPHS, 0, stream>>>(gcnt, ginv);
    k_wc<<<1, 256, 0, stream>>>(W2, Wlin, b2, blin, Wc, bc);

    // gather1 + relu + collapsed layer2 GEMM: bufA -> rbuf (bf16)
    k_g1mm<<<(n + 3) / 4, 256, 0, stream>>>(bufA, ptr, csrc, dinv,
                                            (const float4*)b1, Wc, zrow, rbuf, n);
    // layer2 propagation + mean pool + linear: rbuf -> gsum
    int gwaves = (n + GCH - 1) / GCH;
    k_gpool<<<(gwaves + 3) / 4, 256, 0, stream>>>(rbuf, ptr, csrc, dinv, batch,
                                                  ginv, zrow, gsum, n);
    k_fin2<<<5, 256, 0, stream>>>(gsum, bc, out);
}